// Round 1
// baseline (4488.192 us; speedup 1.0000x reference)
//
#include <hip/hip_runtime.h>
#include <math.h>

// ---------------------------------------------------------------------------
// Problem constants
//   B=4096, IN=10338, H=1024, OUT=229 (216 rotmat + 10 betas + 3 camera)
// Round 0: full-fp32 correctness-first baseline.
//   gemm_bias: 128x64 block tile, BK=16, 256 thr, 8x4 per-thread microtile.
//   BN: 2-stage column stats (mean, rsqrt(var+eps)), fused apply+res+relu.
//   SVD(3x3)->U@Vh replaced by scaled Newton polar iteration (exact same
//   orthogonal factor); sign(det) computed in fp64.
// ---------------------------------------------------------------------------

#define BMT 128
#define BNT 64
#define BKT 16
#define TM 8
#define TN 4

__global__ __launch_bounds__(256)
void gemm_bias(const float* __restrict__ A, const float* __restrict__ B,
               const float* __restrict__ bias, float* __restrict__ C,
               int M, int N, int K) {
  // As transposed [k][m], row stride 132 floats (528B, 16B aligned, 2-way-bank ok)
  __shared__ float As[BKT][BMT + 4];
  __shared__ float Bs[BKT][BNT];
  const int tid = threadIdx.x;
  const int tx = tid & 15;       // N dir, 16 x TN=4 -> 64
  const int ty = tid >> 4;       // M dir, 16 x TM=8 -> 128
  const int bn0 = blockIdx.x * BNT;
  const int bm0 = blockIdx.y * BMT;

  float acc[TM][TN];
#pragma unroll
  for (int i = 0; i < TM; ++i)
#pragma unroll
    for (int j = 0; j < TN; ++j) acc[i][j] = 0.f;

  const int numK = (K + BKT - 1) / BKT;
  for (int kt = 0; kt < numK; ++kt) {
    const int k0 = kt * BKT;
    // stage A: 128x16 = 2048 elems, 8 per thread (64B-coalesced chunks)
#pragma unroll
    for (int r = 0; r < 8; ++r) {
      int idx = tid + r * 256;
      int i = idx >> 4;
      int j = idx & 15;
      int gk = k0 + j;
      float v = 0.f;
      if (gk < K) v = A[(size_t)(bm0 + i) * K + gk];
      As[j][i] = v;
    }
    // stage B: 16x64 = 1024 elems, 4 per thread (256B-coalesced rows)
#pragma unroll
    for (int r = 0; r < 4; ++r) {
      int idx = tid + r * 256;
      int c = idx & 63;
      int j = idx >> 6;
      int gk = k0 + j;
      int gn = bn0 + c;
      float v = 0.f;
      if (gk < K && gn < N) v = B[(size_t)gk * N + gn];
      Bs[j][c] = v;
    }
    __syncthreads();
#pragma unroll
    for (int k = 0; k < BKT; ++k) {
      float a[TM], b[TN];
#pragma unroll
      for (int i = 0; i < TM; ++i) a[i] = As[k][ty * TM + i];
#pragma unroll
      for (int j = 0; j < TN; ++j) b[j] = Bs[k][tx * TN + j];
#pragma unroll
      for (int i = 0; i < TM; ++i)
#pragma unroll
        for (int j = 0; j < TN; ++j)
          acc[i][j] = fmaf(a[i], b[j], acc[i][j]);
    }
    __syncthreads();
  }
  // epilogue: + bias, guarded on N (M=4096 always divides BMT)
#pragma unroll
  for (int j = 0; j < TN; ++j) {
    int gn = bn0 + tx * TN + j;
    if (gn >= N) continue;
    float bs = bias ? bias[gn] : 0.f;
#pragma unroll
    for (int i = 0; i < TM; ++i) {
      int gm = bm0 + ty * TM + i;
      C[(size_t)gm * N + gn] = acc[i][j] + bs;
    }
  }
}

// ---- column stats (mean / rsqrt(var+eps)) over M=4096 rows, N=1024 cols ----
// stage 1: grid (N/64, RG) blocks, each 256 thr = 64 cols x 4 row-lanes
__global__ __launch_bounds__(256)
void colstats_partial(const float* __restrict__ Y, float* __restrict__ psum,
                      float* __restrict__ psq, int N, int rowsPer) {
  const int t = threadIdx.x;
  const int c = blockIdx.x * 64 + (t & 63);
  const int rl = t >> 6;  // 0..3
  const int r0 = blockIdx.y * rowsPer;
  float s = 0.f, q = 0.f;
  for (int r = r0 + rl; r < r0 + rowsPer; r += 4) {
    float v = Y[(size_t)r * N + c];
    s += v;
    q += v * v;
  }
  __shared__ float ls[4][64], lq[4][64];
  ls[rl][t & 63] = s;
  lq[rl][t & 63] = q;
  __syncthreads();
  if (t < 64) {
    float S = ls[0][t] + ls[1][t] + ls[2][t] + ls[3][t];
    float Q = lq[0][t] + lq[1][t] + lq[2][t] + lq[3][t];
    psum[(size_t)blockIdx.y * N + blockIdx.x * 64 + t] = S;
    psq[(size_t)blockIdx.y * N + blockIdx.x * 64 + t] = Q;
  }
}

__global__ void colstats_final(const float* __restrict__ psum,
                               const float* __restrict__ psq,
                               float* __restrict__ mu, float* __restrict__ rstd,
                               int N, int RG, float invM) {
  int c = blockIdx.x * blockDim.x + threadIdx.x;
  if (c >= N) return;
  float s = 0.f, q = 0.f;
  for (int r = 0; r < RG; ++r) {
    s += psum[(size_t)r * N + c];
    q += psq[(size_t)r * N + c];
  }
  float m = s * invM;
  float var = q * invM - m * m;
  mu[c] = m;
  rstd[c] = rsqrtf(var + 1e-5f);
}

// ---- fused BN apply (+optional residual, +optional relu); N must be pow2 ----
__global__ __launch_bounds__(256)
void bn_apply(const float* __restrict__ Y, const float* __restrict__ mu,
              const float* __restrict__ rstd, const float* __restrict__ g,
              const float* __restrict__ be, const float* __restrict__ res,
              float* __restrict__ out, int total, int Nmask, int do_relu) {
  int i = blockIdx.x * blockDim.x + threadIdx.x;
  if (i >= total) return;
  int c = i & Nmask;
  float v = g[c] * (Y[i] - mu[c]) * rstd[c] + be[c];
  if (res) v += res[i];
  if (do_relu) v = fmaxf(v, 0.f);
  out[i] = v;
}

// ---- polar projection of 3x3 (== U@Vh from SVD), times sign(det) ----------
__device__ __forceinline__ void cofactor3(const float X[9], float C[9]) {
  C[0] = X[4] * X[8] - X[5] * X[7];
  C[1] = X[5] * X[6] - X[3] * X[8];
  C[2] = X[3] * X[7] - X[4] * X[6];
  C[3] = X[2] * X[7] - X[1] * X[8];
  C[4] = X[0] * X[8] - X[2] * X[6];
  C[5] = X[1] * X[6] - X[0] * X[7];
  C[6] = X[1] * X[5] - X[2] * X[4];
  C[7] = X[2] * X[3] - X[0] * X[5];
  C[8] = X[0] * X[4] - X[1] * X[3];
}

__global__ __launch_bounds__(256)
void polar_rot(const float* __restrict__ Y, float* __restrict__ out, int nmat,
               int ldy) {
  int idx = blockIdx.x * blockDim.x + threadIdx.x;
  if (idx >= nmat) return;
  int s = idx / 24, j = idx % 24;
  const float* a = Y + (size_t)s * ldy + j * 9;
  float A[9], X[9];
#pragma unroll
  for (int k = 0; k < 9; ++k) {
    A[k] = a[k];
    X[k] = A[k];
  }
  // sign(det(A)) in fp64 (sign discontinuity is the dangerous part)
  double detA = (double)A[0] * ((double)A[4] * A[8] - (double)A[5] * A[7]) -
                (double)A[1] * ((double)A[3] * A[8] - (double)A[5] * A[6]) +
                (double)A[2] * ((double)A[3] * A[7] - (double)A[4] * A[6]);
  float sgn = (detA < 0.0) ? -1.f : 1.f;

  // scaled Newton: X <- 0.5*(zeta*X + (1/zeta)*X^-T), zeta=(|X^-1|F/|X|F)^1/2
#pragma unroll 1
  for (int it = 0; it < 12; ++it) {
    float C[9];
    cofactor3(X, C);
    float det = X[0] * C[0] + X[1] * C[1] + X[2] * C[2];
    float ad = fmaxf(fabsf(det), 1e-30f);
    float idet = (det < 0.f ? -1.f : 1.f) / ad;
    float n1 = 0.f, n2 = 0.f;
#pragma unroll
    for (int k = 0; k < 9; ++k) {
      n1 += X[k] * X[k];
      n2 += C[k] * C[k];
    }
    n1 = fmaxf(n1, 1e-30f);
    float rinv2 = n2 * idet * idet;  // ||X^-1||_F^2
    float zeta = sqrtf(sqrtf(rinv2 / n1));
    zeta = fminf(fmaxf(zeta, 1e-4f), 1e4f);
    float iz = 0.5f / zeta;
    float hz = 0.5f * zeta;
#pragma unroll
    for (int k = 0; k < 9; ++k) X[k] = hz * X[k] + iz * idet * C[k];
  }
  float* o = out + (size_t)idx * 9;
#pragma unroll
  for (int k = 0; k < 9; ++k) o[k] = X[k] * sgn;
}

__global__ void tail_copy(const float* __restrict__ Y, float* __restrict__ out,
                          int Bt, int ldy) {
  int i = blockIdx.x * blockDim.x + threadIdx.x;
  int nb = Bt * 10;
  int nc = Bt * 3;
  if (i < nb) {
    int s = i / 10, k = i % 10;
    out[(size_t)Bt * 216 + i] = Y[(size_t)s * ldy + 216 + k];
  } else if (i < nb + nc) {
    int t = i - nb;
    int s = t / 3, k = t % 3;
    out[(size_t)Bt * 216 + nb + t] = Y[(size_t)s * ldy + 226 + k];
  }
}

// ---------------------------------------------------------------------------
extern "C" void kernel_launch(void* const* d_in, const int* in_sizes, int n_in,
                              void* d_out, int out_size, void* d_ws,
                              size_t ws_size, hipStream_t stream) {
  const float* x = (const float*)d_in[0];
  const float* w1 = (const float*)d_in[1];
  const float* b1 = (const float*)d_in[2];
  const float* g1 = (const float*)d_in[3];
  const float* be1 = (const float*)d_in[4];
  const float* w2a = (const float*)d_in[5];
  const float* b2a = (const float*)d_in[6];
  const float* g2a = (const float*)d_in[7];
  const float* be2a = (const float*)d_in[8];
  const float* w2b = (const float*)d_in[9];
  const float* b2b = (const float*)d_in[10];
  const float* g2b = (const float*)d_in[11];
  const float* be2b = (const float*)d_in[12];
  const float* w3a = (const float*)d_in[13];
  const float* b3a = (const float*)d_in[14];
  const float* g3a = (const float*)d_in[15];
  const float* be3a = (const float*)d_in[16];
  const float* w3b = (const float*)d_in[17];
  const float* b3b = (const float*)d_in[18];
  const float* g3b = (const float*)d_in[19];
  const float* be3b = (const float*)d_in[20];
  const float* w4 = (const float*)d_in[21];
  const float* b4 = (const float*)d_in[22];
  float* out = (float*)d_out;

  const int B = 4096, IN = 10338, H = 1024, OUTN = 229;
  const int RG = 8;

  float* ws = (float*)d_ws;
  float* Y = ws;                       // B*H (reused for final B*OUTN)
  float* Hbuf = Y + (size_t)B * H;     // B*H  (h1 -> h2 -> h3, in-place)
  float* T = Hbuf + (size_t)B * H;     // B*H
  float* psum = T + (size_t)B * H;     // RG*H
  float* psq = psum + (size_t)RG * H;  // RG*H
  float* mu = psq + (size_t)RG * H;    // H
  float* rstd = mu + H;                // H

  auto gemm = [&](const float* Ap, const float* Bp, const float* bias,
                  float* Cp, int N, int K) {
    dim3 grid((N + BNT - 1) / BNT, B / BMT);
    gemm_bias<<<grid, dim3(256), 0, stream>>>(Ap, Bp, bias, Cp, B, N, K);
  };
  auto bnstats = [&](const float* Yp) {
    colstats_partial<<<dim3(H / 64, RG), dim3(256), 0, stream>>>(Yp, psum, psq,
                                                                 H, B / RG);
    colstats_final<<<dim3((H + 255) / 256), dim3(256), 0, stream>>>(
        psum, psq, mu, rstd, H, RG, 1.f / B);
  };
  auto bnapply = [&](const float* Yp, const float* g, const float* be,
                     const float* res, float* op, int relu) {
    int total = B * H;
    bn_apply<<<dim3(total / 256), dim3(256), 0, stream>>>(
        Yp, mu, rstd, g, be, res, op, total, H - 1, relu);
  };

  // layer 1
  gemm(x, w1, b1, Y, H, IN);
  bnstats(Y);
  bnapply(Y, g1, be1, nullptr, Hbuf, 1);
  // resblock 2
  gemm(Hbuf, w2a, b2a, Y, H, H);
  bnstats(Y);
  bnapply(Y, g2a, be2a, nullptr, T, 1);
  gemm(T, w2b, b2b, Y, H, H);
  bnstats(Y);
  bnapply(Y, g2b, be2b, Hbuf, Hbuf, 1);
  // resblock 3
  gemm(Hbuf, w3a, b3a, Y, H, H);
  bnstats(Y);
  bnapply(Y, g3a, be3a, nullptr, T, 1);
  gemm(T, w3b, b3b, Y, H, H);
  bnstats(Y);
  bnapply(Y, g3b, be3b, Hbuf, Hbuf, 1);
  // head
  gemm(Hbuf, w4, b4, Y, OUTN, H);
  int nmat = B * 24;
  polar_rot<<<dim3((nmat + 255) / 256), dim3(256), 0, stream>>>(Y, out, nmat,
                                                                OUTN);
  int ntail = B * 13;
  tail_copy<<<dim3((ntail + 255) / 256), dim3(256), 0, stream>>>(Y, out, B,
                                                                 OUTN);
}

// Round 2
// 1550.982 us; speedup vs baseline: 2.8938x; 2.8938x over previous
//
#include <hip/hip_runtime.h>
#include <math.h>

// ---------------------------------------------------------------------------
// B=4096, IN=10338 (pad 10368), H=1024, OUT=229 (pad 256)
// R2: f16x3 split-MFMA GEMM (fp32-equivalent accuracy via scaled-lo split),
//     m97 structure: 128x128 tile, BK=32, global_load_lds(16B), split-K.
// ---------------------------------------------------------------------------

typedef _Float16 half8 __attribute__((ext_vector_type(8)));
typedef float floatx4 __attribute__((ext_vector_type(4)));

#define LO_SCALE 4096.0f
#define LO_INV (1.0f / 4096.0f)

__device__ __forceinline__ void gld16(const _Float16* g, _Float16* l) {
  __builtin_amdgcn_global_load_lds(
      (const __attribute__((address_space(1))) void*)g,
      (__attribute__((address_space(3))) void*)l, 16, 0, 0);
}

// C_partial[z] = A[M x Ks] * BT[N x Ks]^T   (f16 hi/lo pairs, lo prescaled)
// A row stride = Kld, BT row stride = Kld. Partial stride = partStride floats.
__global__ __launch_bounds__(256)
void gemm_sk(const _Float16* __restrict__ Ah, const _Float16* __restrict__ Al,
             const _Float16* __restrict__ Bh, const _Float16* __restrict__ Bl,
             float* __restrict__ Cp, int Kld, int Ncols, int Ks,
             size_t partStride) {
  __shared__ _Float16 sAh[128 * 32], sAl[128 * 32];
  __shared__ _Float16 sBh[128 * 32], sBl[128 * 32];
  const int tid = threadIdx.x;
  const int wv = tid >> 6, ln = tid & 63;
  const int ln15 = ln & 15, q = ln >> 4;
  const int wr = wv >> 1, wc = wv & 1;
  const int bm0 = blockIdx.x * 128, bn0 = blockIdx.y * 128;
  const int k0 = blockIdx.z * Ks;
  Cp += (size_t)blockIdx.z * partStride;

  floatx4 acc[4][4];   // hi*hi
  floatx4 acc2[4][4];  // cross terms (scaled by LO_SCALE)
#pragma unroll
  for (int i = 0; i < 4; ++i)
#pragma unroll
    for (int j = 0; j < 4; ++j) {
      acc[i][j] = (floatx4){0.f, 0.f, 0.f, 0.f};
      acc2[i][j] = (floatx4){0.f, 0.f, 0.f, 0.f};
    }

  // staging: 8KB/tile, 4 tiles; wave wv stages chunks {2wv, 2wv+1} of each.
  const int srow = ln >> 2;        // 0..15  (row within 16-row chunk)
  const int scol = (ln & 3) * 8;   // half-index within 32-k row
  const _Float16* gAh = Ah + (size_t)bm0 * Kld + k0 + scol;
  const _Float16* gAl = Al + (size_t)bm0 * Kld + k0 + scol;
  const _Float16* gBh = Bh + (size_t)bn0 * Kld + k0 + scol;
  const _Float16* gBl = Bl + (size_t)bn0 * Kld + k0 + scol;

  for (int kt = 0; kt < Ks; kt += 32) {
    __syncthreads();
#pragma unroll
    for (int l = 0; l < 2; ++l) {
      const int ch = wv * 2 + l;
      const size_t go = (size_t)(ch * 16 + srow) * Kld + kt;
      gld16(gAh + go, &sAh[ch * 512]);
      gld16(gAl + go, &sAl[ch * 512]);
      gld16(gBh + go, &sBh[ch * 512]);
      gld16(gBl + go, &sBl[ch * 512]);
    }
    __syncthreads();

    half8 ah[4], al[4], bh[4], bl[4];
#pragma unroll
    for (int mi = 0; mi < 4; ++mi) {
      const int o = (wr * 64 + mi * 16 + ln15) * 32 + q * 8;
      ah[mi] = *(const half8*)&sAh[o];
      al[mi] = *(const half8*)&sAl[o];
    }
#pragma unroll
    for (int ni = 0; ni < 4; ++ni) {
      const int o = (wc * 64 + ni * 16 + ln15) * 32 + q * 8;
      bh[ni] = *(const half8*)&sBh[o];
      bl[ni] = *(const half8*)&sBl[o];
    }
#pragma unroll
    for (int mi = 0; mi < 4; ++mi)
#pragma unroll
      for (int ni = 0; ni < 4; ++ni) {
        acc[mi][ni] = __builtin_amdgcn_mfma_f32_16x16x32_f16(
            ah[mi], bh[ni], acc[mi][ni], 0, 0, 0);
        acc2[mi][ni] = __builtin_amdgcn_mfma_f32_16x16x32_f16(
            ah[mi], bl[ni], acc2[mi][ni], 0, 0, 0);
        acc2[mi][ni] = __builtin_amdgcn_mfma_f32_16x16x32_f16(
            al[mi], bh[ni], acc2[mi][ni], 0, 0, 0);
      }
  }

  // C/D layout: col = lane&15, row = (lane>>4)*4 + reg  [m89-verified]
#pragma unroll
  for (int mi = 0; mi < 4; ++mi)
#pragma unroll
    for (int ni = 0; ni < 4; ++ni) {
      const int col = bn0 + wc * 64 + ni * 16 + ln15;
      if (col < Ncols) {
        const int rbase = bm0 + wr * 64 + mi * 16 + q * 4;
#pragma unroll
        for (int r = 0; r < 4; ++r)
          Cp[(size_t)(rbase + r) * Ncols + col] =
              acc[mi][ni][r] + acc2[mi][ni][r] * LO_INV;
      }
    }
}

__global__ void reduce_bias(const float* __restrict__ Cp,
                            const float* __restrict__ bias,
                            float* __restrict__ Y, int total, int Ncols, int S,
                            size_t stride) {
  int i = blockIdx.x * 256 + threadIdx.x;
  if (i >= total) return;
  float s = 0.f;
  for (int k = 0; k < S; ++k) s += Cp[(size_t)k * stride + i];
  Y[i] = s + bias[i % Ncols];
}

// ---- fp32 -> f16 hi/lo split, zero-padded to Kpad ----
__global__ void split_pad(const float* __restrict__ X, _Float16* __restrict__ xh,
                          _Float16* __restrict__ xl, int K, int Kpad,
                          int total) {
  int i = blockIdx.x * 256 + threadIdx.x;
  if (i >= total) return;
  int row = i / Kpad;
  int col = i - row * Kpad;
  float v = (col < K) ? X[(size_t)row * K + col] : 0.f;
  _Float16 h = (_Float16)v;
  xh[i] = h;
  xl[i] = (_Float16)((v - (float)h) * LO_SCALE);
}

// ---- W[K][N] fp32 -> WT[Npad][Kpad] f16 hi/lo (zero pad) ----
__global__ void transpose_split(const float* __restrict__ W,
                                _Float16* __restrict__ th,
                                _Float16* __restrict__ tl, int K, int N,
                                int Kpad, int Npad) {
  __shared__ float ts[32][33];
  const int tx = threadIdx.x, ty = threadIdx.y;  // 32 x 8
  const int k0 = blockIdx.x * 32, n0 = blockIdx.y * 32;
#pragma unroll
  for (int r = 0; r < 4; ++r) {
    int kk = k0 + ty + r * 8;
    int nn = n0 + tx;
    float v = (kk < K && nn < N) ? W[(size_t)kk * N + nn] : 0.f;
    ts[ty + r * 8][tx] = v;
  }
  __syncthreads();
#pragma unroll
  for (int r = 0; r < 4; ++r) {
    int nn = n0 + ty + r * 8;
    int kk = k0 + tx;
    float v = ts[tx][ty + r * 8];
    _Float16 h = (_Float16)v;
    size_t o = (size_t)nn * Kpad + kk;
    th[o] = h;
    tl[o] = (_Float16)((v - (float)h) * LO_SCALE);
  }
}

// ---- column stats over M rows ----
__global__ __launch_bounds__(256)
void colstats_partial(const float* __restrict__ Y, float* __restrict__ psum,
                      float* __restrict__ psq, int N, int rowsPer) {
  const int t = threadIdx.x;
  const int c = blockIdx.x * 64 + (t & 63);
  const int rl = t >> 6;
  const int r0 = blockIdx.y * rowsPer;
  float s = 0.f, qq = 0.f;
  for (int r = r0 + rl; r < r0 + rowsPer; r += 4) {
    float v = Y[(size_t)r * N + c];
    s += v;
    qq += v * v;
  }
  __shared__ float ls[4][64], lq[4][64];
  ls[rl][t & 63] = s;
  lq[rl][t & 63] = qq;
  __syncthreads();
  if (t < 64) {
    psum[(size_t)blockIdx.y * N + blockIdx.x * 64 + t] =
        ls[0][t] + ls[1][t] + ls[2][t] + ls[3][t];
    psq[(size_t)blockIdx.y * N + blockIdx.x * 64 + t] =
        lq[0][t] + lq[1][t] + lq[2][t] + lq[3][t];
  }
}

__global__ void colstats_final(const float* __restrict__ psum,
                               const float* __restrict__ psq,
                               float* __restrict__ mu, float* __restrict__ rstd,
                               int N, int RG, float invM) {
  int c = blockIdx.x * blockDim.x + threadIdx.x;
  if (c >= N) return;
  float s = 0.f, qq = 0.f;
  for (int r = 0; r < RG; ++r) {
    s += psum[(size_t)r * N + c];
    qq += psq[(size_t)r * N + c];
  }
  float m = s * invM;
  mu[c] = m;
  rstd[c] = rsqrtf(qq * invM - m * m + 1e-5f);
}

// ---- BN apply (+res,+relu) fused with f16 hi/lo split of the output ----
__global__ __launch_bounds__(256)
void bn_apply_split(const float* __restrict__ Y, const float* __restrict__ mu,
                    const float* __restrict__ rstd, const float* __restrict__ g,
                    const float* __restrict__ be, const float* __restrict__ res,
                    float* __restrict__ outf, _Float16* __restrict__ oh,
                    _Float16* __restrict__ ol, int total, int Nmask,
                    int do_relu) {
  int i = blockIdx.x * 256 + threadIdx.x;
  if (i >= total) return;
  int c = i & Nmask;
  float v = g[c] * (Y[i] - mu[c]) * rstd[c] + be[c];
  if (res) v += res[i];
  if (do_relu) v = fmaxf(v, 0.f);
  if (outf) outf[i] = v;
  _Float16 h = (_Float16)v;
  oh[i] = h;
  ol[i] = (_Float16)((v - (float)h) * LO_SCALE);
}

// ---- polar projection (== U@Vh) * sign(det) ----
__device__ __forceinline__ void cofactor3(const float X[9], float C[9]) {
  C[0] = X[4] * X[8] - X[5] * X[7];
  C[1] = X[5] * X[6] - X[3] * X[8];
  C[2] = X[3] * X[7] - X[4] * X[6];
  C[3] = X[2] * X[7] - X[1] * X[8];
  C[4] = X[0] * X[8] - X[2] * X[6];
  C[5] = X[1] * X[6] - X[0] * X[7];
  C[6] = X[1] * X[5] - X[2] * X[4];
  C[7] = X[2] * X[3] - X[0] * X[5];
  C[8] = X[0] * X[4] - X[1] * X[3];
}

__global__ __launch_bounds__(256)
void polar_rot(const float* __restrict__ Y, float* __restrict__ out, int nmat,
               int ldy) {
  int idx = blockIdx.x * blockDim.x + threadIdx.x;
  if (idx >= nmat) return;
  int s = idx / 24, j = idx % 24;
  const float* a = Y + (size_t)s * ldy + j * 9;
  float A[9], X[9];
#pragma unroll
  for (int k = 0; k < 9; ++k) {
    A[k] = a[k];
    X[k] = A[k];
  }
  double detA = (double)A[0] * ((double)A[4] * A[8] - (double)A[5] * A[7]) -
                (double)A[1] * ((double)A[3] * A[8] - (double)A[5] * A[6]) +
                (double)A[2] * ((double)A[3] * A[7] - (double)A[4] * A[6]);
  float sgn = (detA < 0.0) ? -1.f : 1.f;

#pragma unroll 1
  for (int it = 0; it < 12; ++it) {
    float C[9];
    cofactor3(X, C);
    float det = X[0] * C[0] + X[1] * C[1] + X[2] * C[2];
    float ad = fmaxf(fabsf(det), 1e-30f);
    float idet = (det < 0.f ? -1.f : 1.f) / ad;
    float n1 = 0.f, n2 = 0.f;
#pragma unroll
    for (int k = 0; k < 9; ++k) {
      n1 += X[k] * X[k];
      n2 += C[k] * C[k];
    }
    n1 = fmaxf(n1, 1e-30f);
    float zeta = sqrtf(sqrtf(n2 * idet * idet / n1));
    zeta = fminf(fmaxf(zeta, 1e-4f), 1e4f);
    float iz = 0.5f / zeta;
    float hz = 0.5f * zeta;
#pragma unroll
    for (int k = 0; k < 9; ++k) X[k] = hz * X[k] + iz * idet * C[k];
  }
  float* o = out + (size_t)idx * 9;
#pragma unroll
  for (int k = 0; k < 9; ++k) o[k] = X[k] * sgn;
}

__global__ void tail_copy(const float* __restrict__ Y, float* __restrict__ out,
                          int Bt, int ldy) {
  int i = blockIdx.x * blockDim.x + threadIdx.x;
  int nb = Bt * 10;
  int nc = Bt * 3;
  if (i < nb) {
    int s = i / 10, k = i % 10;
    out[(size_t)Bt * 216 + i] = Y[(size_t)s * ldy + 216 + k];
  } else if (i < nb + nc) {
    int t = i - nb;
    int s = t / 3, k = t % 3;
    out[(size_t)Bt * 216 + nb + t] = Y[(size_t)s * ldy + 226 + k];
  }
}

// ---------------------------------------------------------------------------
extern "C" void kernel_launch(void* const* d_in, const int* in_sizes, int n_in,
                              void* d_out, int out_size, void* d_ws,
                              size_t ws_size, hipStream_t stream) {
  const float* x = (const float*)d_in[0];
  const float* w1 = (const float*)d_in[1];
  const float* b1 = (const float*)d_in[2];
  const float* g1 = (const float*)d_in[3];
  const float* be1 = (const float*)d_in[4];
  const float* w2a = (const float*)d_in[5];
  const float* b2a = (const float*)d_in[6];
  const float* g2a = (const float*)d_in[7];
  const float* be2a = (const float*)d_in[8];
  const float* w2b = (const float*)d_in[9];
  const float* b2b = (const float*)d_in[10];
  const float* g2b = (const float*)d_in[11];
  const float* be2b = (const float*)d_in[12];
  const float* w3a = (const float*)d_in[13];
  const float* b3a = (const float*)d_in[14];
  const float* g3a = (const float*)d_in[15];
  const float* be3a = (const float*)d_in[16];
  const float* w3b = (const float*)d_in[17];
  const float* b3b = (const float*)d_in[18];
  const float* g3b = (const float*)d_in[19];
  const float* be3b = (const float*)d_in[20];
  const float* w4 = (const float*)d_in[21];
  const float* b4 = (const float*)d_in[22];
  float* out = (float*)d_out;

  const int B = 4096, IN = 10338, INP = 10368, H = 1024;
  const int OUTN = 229, OUTP = 256;
  const int RG = 8;
  const int S_BIG = 4, S_MID = 2, S_HEAD = 4;

  // workspace carve (256B aligned)
  char* p = (char*)d_ws;
  auto alloc = [&](size_t bytes) -> void* {
    void* r = (void*)p;
    p += (bytes + 255) & ~(size_t)255;
    return r;
  };
  float* Cpart = (float*)alloc((size_t)S_BIG * B * H * 4);
  float* Y = (float*)alloc((size_t)B * H * 4);
  float* Hf = (float*)alloc((size_t)B * H * 4);
  _Float16* xh = (_Float16*)alloc((size_t)B * INP * 2);
  _Float16* xl = (_Float16*)alloc((size_t)B * INP * 2);
  _Float16* w1h = (_Float16*)alloc((size_t)H * INP * 2);
  _Float16* w1l = (_Float16*)alloc((size_t)H * INP * 2);
  _Float16* wmh[4], *wml[4];
  for (int i = 0; i < 4; ++i) {
    wmh[i] = (_Float16*)alloc((size_t)H * H * 2);
    wml[i] = (_Float16*)alloc((size_t)H * H * 2);
  }
  _Float16* w4h = (_Float16*)alloc((size_t)OUTP * H * 2);
  _Float16* w4l = (_Float16*)alloc((size_t)OUTP * H * 2);
  _Float16* hh = (_Float16*)alloc((size_t)B * H * 2);
  _Float16* hl = (_Float16*)alloc((size_t)B * H * 2);
  float* psum = (float*)alloc((size_t)RG * H * 4);
  float* psq = (float*)alloc((size_t)RG * H * 4);
  float* mu = (float*)alloc(H * 4);
  float* rstd = (float*)alloc(H * 4);

  // ---- input conversions ----
  {
    int total = B * INP;
    split_pad<<<dim3((total + 255) / 256), 256, 0, stream>>>(x, xh, xl, IN,
                                                             INP, total);
    transpose_split<<<dim3(INP / 32, H / 32), dim3(32, 8), 0, stream>>>(
        w1, w1h, w1l, IN, H, INP, H);
    const float* wm[4] = {w2a, w2b, w3a, w3b};
    for (int i = 0; i < 4; ++i)
      transpose_split<<<dim3(H / 32, H / 32), dim3(32, 8), 0, stream>>>(
          wm[i], wmh[i], wml[i], H, H, H, H);
    transpose_split<<<dim3(H / 32, OUTP / 32), dim3(32, 8), 0, stream>>>(
        w4, w4h, w4l, H, OUTN, H, OUTP);
  }

  auto gemm = [&](const _Float16* Ah, const _Float16* Al, const _Float16* Bh,
                  const _Float16* Bl, const float* bias, int Kld, int Npad,
                  int Ncols, int S) {
    size_t stride = (size_t)B * Ncols;
    gemm_sk<<<dim3(B / 128, Npad / 128, S), 256, 0, stream>>>(
        Ah, Al, Bh, Bl, Cpart, Kld, Ncols, Kld / S, stride);
    int total = B * Ncols;
    reduce_bias<<<dim3((total + 255) / 256), 256, 0, stream>>>(
        Cpart, bias, Y, total, Ncols, S, stride);
  };
  auto bnstats = [&]() {
    colstats_partial<<<dim3(H / 64, RG), 256, 0, stream>>>(Y, psum, psq, H,
                                                           B / RG);
    colstats_final<<<dim3((H + 255) / 256), 256, 0, stream>>>(psum, psq, mu,
                                                              rstd, H, RG,
                                                              1.f / B);
  };
  auto bnapply = [&](const float* g, const float* be, const float* res,
                     float* outf) {
    int total = B * H;
    bn_apply_split<<<dim3(total / 256), 256, 0, stream>>>(
        Y, mu, rstd, g, be, res, outf, hh, hl, total, H - 1, 1);
  };

  // layer 1
  gemm(xh, xl, w1h, w1l, b1, INP, H, H, S_BIG);
  bnstats();
  bnapply(g1, be1, nullptr, Hf);  // h1 -> Hf + split
  // resblock 2
  gemm(hh, hl, wmh[0], wml[0], b2a, H, H, H, S_MID);
  bnstats();
  bnapply(g2a, be2a, nullptr, nullptr);  // t -> split only
  gemm(hh, hl, wmh[1], wml[1], b2b, H, H, H, S_MID);
  bnstats();
  bnapply(g2b, be2b, Hf, Hf);  // h2 = relu(h1 + bn) -> Hf + split
  // resblock 3
  gemm(hh, hl, wmh[2], wml[2], b3a, H, H, H, S_MID);
  bnstats();
  bnapply(g3a, be3a, nullptr, nullptr);
  gemm(hh, hl, wmh[3], wml[3], b3b, H, H, H, S_MID);
  bnstats();
  bnapply(g3b, be3b, Hf, Hf);  // h3
  // head
  gemm(hh, hl, w4h, w4l, b4, H, OUTP, OUTN, S_HEAD);

  int nmat = B * 24;
  polar_rot<<<dim3((nmat + 255) / 256), 256, 0, stream>>>(Y, out, nmat, OUTN);
  int ntail = B * 13;
  tail_copy<<<dim3((ntail + 255) / 256), 256, 0, stream>>>(Y, out, B, OUTN);
}

// Round 3
// 1443.269 us; speedup vs baseline: 3.1097x; 1.0746x over previous
//
#include <hip/hip_runtime.h>
#include <math.h>

// ---------------------------------------------------------------------------
// B=4096, IN=10338 (pad 10368), H=1024, OUT=229 (pad 256)
// R3: f16x3 split-MFMA GEMM with
//   - XOR-swizzled LDS K-chunks (kills 8-way bank conflicts; 2-way is free)
//   - double-buffered LDS (2x32KB), stage-next-before-compute pipeline
//   - __launch_bounds__(256,2) to force 2 waves/SIMD (128 AGPR acc + <=128 arch)
//   - fused reduce+bias+stats, BN-finalize in bn_apply, polar+tail merged
// ---------------------------------------------------------------------------

typedef _Float16 half8 __attribute__((ext_vector_type(8)));
typedef float floatx4 __attribute__((ext_vector_type(4)));

#define LO_SCALE 4096.0f
#define LO_INV (1.0f / 4096.0f)

__device__ __forceinline__ void gld16(const _Float16* g, _Float16* l) {
  __builtin_amdgcn_global_load_lds(
      (const __attribute__((address_space(1))) void*)g,
      (__attribute__((address_space(3))) void*)l, 16, 0, 0);
}

// C_partial[z] = A[M x Ks] * BT[N x Ks]^T  (f16 hi/lo, lo prescaled by 4096)
__global__ __launch_bounds__(256, 2)
void gemm_sk(const _Float16* __restrict__ Ah, const _Float16* __restrict__ Al,
             const _Float16* __restrict__ Bh, const _Float16* __restrict__ Bl,
             float* __restrict__ Cp, int Kld, int Ncols, int Ks,
             size_t partStride) {
  // 2 buffers x 4 arrays x 128x32 halves = 64 KB
  __shared__ _Float16 sAh[2][4096], sAl[2][4096];
  __shared__ _Float16 sBh[2][4096], sBl[2][4096];
  const int tid = threadIdx.x;
  const int wv = tid >> 6, ln = tid & 63;
  const int ln15 = ln & 15, q = ln >> 4;
  const int wr = wv >> 1, wc = wv & 1;
  const int bm0 = blockIdx.x * 128, bn0 = blockIdx.y * 128;
  const int k0 = blockIdx.z * Ks;
  Cp += (size_t)blockIdx.z * partStride;

  // ---- staging addressing (source-permuted for XOR-swizzled LDS layout) ----
  // lane ln writes LDS offset ln*8 halves within its chunk (HW: base+lane*16B)
  // => (row srow=ln>>2, phys kchunk c=ln&3). It must fetch logical kchunk
  //    qsrc = c ^ (srow&3) ^ ((srow>>2)&3)  so reads can de-swizzle.
  const int srow = ln >> 2;
  const int swzw = (ln & 3) ^ (srow & 3) ^ ((srow >> 2) & 3);
  const int ch0 = wv * 2, ch1 = wv * 2 + 1;
  const size_t offA0 = (size_t)(bm0 + ch0 * 16 + srow) * Kld + k0 + swzw * 8;
  const size_t offA1 = (size_t)(bm0 + ch1 * 16 + srow) * Kld + k0 + swzw * 8;
  const size_t offB0 = (size_t)(bn0 + ch0 * 16 + srow) * Kld + k0 + swzw * 8;
  const size_t offB1 = (size_t)(bn0 + ch1 * 16 + srow) * Kld + k0 + swzw * 8;

  // ---- fragment read addressing (de-swizzle, independent of mi/ni) ----
  const int swzr = (q ^ (ln15 & 3) ^ ((ln15 >> 2) & 3)) * 8;
  const int aoff = (wr * 64 + ln15) * 32 + swzr;
  const int boff = (wc * 64 + ln15) * 32 + swzr;

  floatx4 acc[4][4];   // hi*hi
  floatx4 acc2[4][4];  // cross terms (scaled by LO_SCALE)
#pragma unroll
  for (int i = 0; i < 4; ++i)
#pragma unroll
    for (int j = 0; j < 4; ++j) {
      acc[i][j] = (floatx4){0.f, 0.f, 0.f, 0.f};
      acc2[i][j] = (floatx4){0.f, 0.f, 0.f, 0.f};
    }

  auto stage = [&](int kt, int buf) {
    gld16(Ah + offA0 + kt, &sAh[buf][ch0 * 512]);
    gld16(Ah + offA1 + kt, &sAh[buf][ch1 * 512]);
    gld16(Al + offA0 + kt, &sAl[buf][ch0 * 512]);
    gld16(Al + offA1 + kt, &sAl[buf][ch1 * 512]);
    gld16(Bh + offB0 + kt, &sBh[buf][ch0 * 512]);
    gld16(Bh + offB1 + kt, &sBh[buf][ch1 * 512]);
    gld16(Bl + offB0 + kt, &sBl[buf][ch0 * 512]);
    gld16(Bl + offB1 + kt, &sBl[buf][ch1 * 512]);
  };

  stage(0, 0);
  int cur = 0;
  for (int kt = 0; kt < Ks; kt += 32) {
    __syncthreads();  // buf[cur] staged; prior reads of buf[cur^1] done
    if (kt + 32 < Ks) stage(kt + 32, cur ^ 1);  // async, overlaps compute

    const _Float16* pAh = &sAh[cur][aoff];
    const _Float16* pAl = &sAl[cur][aoff];
    const _Float16* pBh = &sBh[cur][boff];
    const _Float16* pBl = &sBl[cur][boff];
    half8 bh[4], bl[4];
#pragma unroll
    for (int ni = 0; ni < 4; ++ni) {
      bh[ni] = *(const half8*)(pBh + ni * 512);
      bl[ni] = *(const half8*)(pBl + ni * 512);
    }
#pragma unroll
    for (int mh = 0; mh < 2; ++mh) {
      half8 ah[2], al[2];
#pragma unroll
      for (int i = 0; i < 2; ++i) {
        ah[i] = *(const half8*)(pAh + (mh * 2 + i) * 512);
        al[i] = *(const half8*)(pAl + (mh * 2 + i) * 512);
      }
#pragma unroll
      for (int i = 0; i < 2; ++i) {
        const int mi = mh * 2 + i;
#pragma unroll
        for (int ni = 0; ni < 4; ++ni) {
          acc[mi][ni] = __builtin_amdgcn_mfma_f32_16x16x32_f16(
              ah[i], bh[ni], acc[mi][ni], 0, 0, 0);
          acc2[mi][ni] = __builtin_amdgcn_mfma_f32_16x16x32_f16(
              ah[i], bl[ni], acc2[mi][ni], 0, 0, 0);
          acc2[mi][ni] = __builtin_amdgcn_mfma_f32_16x16x32_f16(
              al[i], bh[ni], acc2[mi][ni], 0, 0, 0);
        }
      }
    }
    cur ^= 1;
  }

  // C/D layout: col = lane&15, row = (lane>>4)*4 + reg  [m89-verified]
  // Ncols always padded to a multiple of 128 here -> no guard.
#pragma unroll
  for (int mi = 0; mi < 4; ++mi)
#pragma unroll
    for (int ni = 0; ni < 4; ++ni) {
      const int col = bn0 + wc * 64 + ni * 16 + ln15;
      const int rbase = bm0 + wr * 64 + mi * 16 + q * 4;
#pragma unroll
      for (int r = 0; r < 4; ++r)
        Cp[(size_t)(rbase + r) * Ncols + col] =
            acc[mi][ni][r] + acc2[mi][ni][r] * LO_INV;
    }
}

// ---- fused: sum split-K partials + bias -> Y, and per-rowblock col stats ----
__global__ __launch_bounds__(256)
void reduce_bias_stats(const float* __restrict__ Cp,
                       const float* __restrict__ bias, float* __restrict__ Y,
                       float* __restrict__ psum, float* __restrict__ psq, int N,
                       int S, size_t stride, int rowsPer) {
  const int t = threadIdx.x;
  const int c = blockIdx.x * 64 + (t & 63);
  const int rl = t >> 6;
  const int r0 = blockIdx.y * rowsPer;
  const float bs = bias[c];
  float s = 0.f, qq = 0.f;
  for (int r = r0 + rl; r < r0 + rowsPer; r += 4) {
    size_t i = (size_t)r * N + c;
    float v = bs;
    for (int k = 0; k < S; ++k) v += Cp[(size_t)k * stride + i];
    Y[i] = v;
    s += v;
    qq += v * v;
  }
  __shared__ float ls[4][64], lq[4][64];
  ls[rl][t & 63] = s;
  lq[rl][t & 63] = qq;
  __syncthreads();
  if (t < 64) {
    psum[(size_t)blockIdx.y * N + blockIdx.x * 64 + t] =
        ls[0][t] + ls[1][t] + ls[2][t] + ls[3][t];
    psq[(size_t)blockIdx.y * N + blockIdx.x * 64 + t] =
        lq[0][t] + lq[1][t] + lq[2][t] + lq[3][t];
  }
}

// ---- head reduce (no BN): partials + guarded bias -> Y ----
__global__ void reduce_bias_head(const float* __restrict__ Cp,
                                 const float* __restrict__ bias,
                                 float* __restrict__ Y, int total, int Ncols,
                                 int biasN, int S, size_t stride) {
  int i = blockIdx.x * 256 + threadIdx.x;
  if (i >= total) return;
  int c = i % Ncols;
  float v = (c < biasN) ? bias[c] : 0.f;
  for (int k = 0; k < S; ++k) v += Cp[(size_t)k * stride + i];
  Y[i] = v;
}

// ---- BN finalize+apply (+res, relu) fused with f16 hi/lo split ----
// grid (N/256, B/4); block handles 256 cols x 4 rows
__global__ __launch_bounds__(256)
void bn_apply_split(const float* __restrict__ Y, const float* __restrict__ psum,
                    const float* __restrict__ psq, const float* __restrict__ g,
                    const float* __restrict__ be, const float* __restrict__ res,
                    float* __restrict__ outf, _Float16* __restrict__ oh,
                    _Float16* __restrict__ ol, int N, int RB, float invM) {
  const int c = blockIdx.x * 256 + threadIdx.x;
  float s = 0.f, qq = 0.f;
  for (int rb = 0; rb < RB; ++rb) {
    s += psum[(size_t)rb * N + c];
    qq += psq[(size_t)rb * N + c];
  }
  const float m = s * invM;
  const float rstd = rsqrtf(qq * invM - m * m + 1e-5f);
  const float a = g[c] * rstd;
  const float b2 = be[c] - m * a;
#pragma unroll
  for (int r = 0; r < 4; ++r) {
    size_t i = (size_t)(blockIdx.y * 4 + r) * N + c;
    float v = Y[i] * a + b2;
    if (res) v += res[i];
    v = fmaxf(v, 0.f);
    if (outf) outf[i] = v;
    _Float16 h = (_Float16)v;
    oh[i] = h;
    ol[i] = (_Float16)((v - (float)h) * LO_SCALE);
  }
}

// ---- fp32 -> f16 hi/lo split, zero-padded to Kpad ----
__global__ void split_pad(const float* __restrict__ X,
                          _Float16* __restrict__ xh, _Float16* __restrict__ xl,
                          int K, int Kpad, int total) {
  int i = blockIdx.x * 256 + threadIdx.x;
  if (i >= total) return;
  int row = i / Kpad;
  int col = i - row * Kpad;
  float v = (col < K) ? X[(size_t)row * K + col] : 0.f;
  _Float16 h = (_Float16)v;
  xh[i] = h;
  xl[i] = (_Float16)((v - (float)h) * LO_SCALE);
}

// ---- W[K][N] fp32 -> WT[Npad][Kpad] f16 hi/lo (zero pad) ----
__global__ void transpose_split(const float* __restrict__ W,
                                _Float16* __restrict__ th,
                                _Float16* __restrict__ tl, int K, int N,
                                int Kpad, int Npad) {
  __shared__ float ts[32][33];
  const int tx = threadIdx.x, ty = threadIdx.y;  // 32 x 8
  const int k0 = blockIdx.x * 32, n0 = blockIdx.y * 32;
#pragma unroll
  for (int r = 0; r < 4; ++r) {
    int kk = k0 + ty + r * 8;
    int nn = n0 + tx;
    float v = (kk < K && nn < N) ? W[(size_t)kk * N + nn] : 0.f;
    ts[ty + r * 8][tx] = v;
  }
  __syncthreads();
#pragma unroll
  for (int r = 0; r < 4; ++r) {
    int nn = n0 + ty + r * 8;
    int kk = k0 + tx;
    float v = ts[tx][ty + r * 8];
    _Float16 h = (_Float16)v;
    size_t o = (size_t)nn * Kpad + kk;
    th[o] = h;
    tl[o] = (_Float16)((v - (float)h) * LO_SCALE);
  }
}

// ---- polar projection (== U@Vh from SVD) * sign(det), fused with tail ----
__device__ __forceinline__ void cofactor3(const float X[9], float C[9]) {
  C[0] = X[4] * X[8] - X[5] * X[7];
  C[1] = X[5] * X[6] - X[3] * X[8];
  C[2] = X[3] * X[7] - X[4] * X[6];
  C[3] = X[2] * X[7] - X[1] * X[8];
  C[4] = X[0] * X[8] - X[2] * X[6];
  C[5] = X[1] * X[6] - X[0] * X[7];
  C[6] = X[1] * X[5] - X[2] * X[4];
  C[7] = X[2] * X[3] - X[0] * X[5];
  C[8] = X[0] * X[4] - X[1] * X[3];
}

__global__ __launch_bounds__(256)
void polar_tail(const float* __restrict__ Y, float* __restrict__ out, int Bt,
                int nmat, int ldy) {
  int idx = blockIdx.x * blockDim.x + threadIdx.x;
  if (idx < nmat) {
    int s = idx / 24, j = idx % 24;
    const float* a = Y + (size_t)s * ldy + j * 9;
    float A[9], X[9];
#pragma unroll
    for (int k = 0; k < 9; ++k) {
      A[k] = a[k];
      X[k] = A[k];
    }
    double detA = (double)A[0] * ((double)A[4] * A[8] - (double)A[5] * A[7]) -
                  (double)A[1] * ((double)A[3] * A[8] - (double)A[5] * A[6]) +
                  (double)A[2] * ((double)A[3] * A[7] - (double)A[4] * A[6]);
    float sgn = (detA < 0.0) ? -1.f : 1.f;
#pragma unroll 1
    for (int it = 0; it < 12; ++it) {
      float C[9];
      cofactor3(X, C);
      float det = X[0] * C[0] + X[1] * C[1] + X[2] * C[2];
      float ad = fmaxf(fabsf(det), 1e-30f);
      float idet = (det < 0.f ? -1.f : 1.f) / ad;
      float n1 = 0.f, n2 = 0.f;
#pragma unroll
      for (int k = 0; k < 9; ++k) {
        n1 += X[k] * X[k];
        n2 += C[k] * C[k];
      }
      n1 = fmaxf(n1, 1e-30f);
      float zeta = sqrtf(sqrtf(n2 * idet * idet / n1));
      zeta = fminf(fmaxf(zeta, 1e-4f), 1e4f);
      float iz = 0.5f / zeta;
      float hz = 0.5f * zeta;
#pragma unroll
      for (int k = 0; k < 9; ++k) X[k] = hz * X[k] + iz * idet * C[k];
    }
    float* o = out + (size_t)idx * 9;
#pragma unroll
    for (int k = 0; k < 9; ++k) o[k] = X[k] * sgn;
  } else {
    int i = idx - nmat;
    int nb = Bt * 10;
    int nc = Bt * 3;
    if (i < nb) {
      int s = i / 10, k = i % 10;
      out[(size_t)Bt * 216 + i] = Y[(size_t)s * ldy + 216 + k];
    } else if (i < nb + nc) {
      int t = i - nb;
      int s = t / 3, k = t % 3;
      out[(size_t)Bt * 216 + nb + t] = Y[(size_t)s * ldy + 226 + k];
    }
  }
}

// ---------------------------------------------------------------------------
extern "C" void kernel_launch(void* const* d_in, const int* in_sizes, int n_in,
                              void* d_out, int out_size, void* d_ws,
                              size_t ws_size, hipStream_t stream) {
  const float* x = (const float*)d_in[0];
  const float* w1 = (const float*)d_in[1];
  const float* b1 = (const float*)d_in[2];
  const float* g1 = (const float*)d_in[3];
  const float* be1 = (const float*)d_in[4];
  const float* w2a = (const float*)d_in[5];
  const float* b2a = (const float*)d_in[6];
  const float* g2a = (const float*)d_in[7];
  const float* be2a = (const float*)d_in[8];
  const float* w2b = (const float*)d_in[9];
  const float* b2b = (const float*)d_in[10];
  const float* g2b = (const float*)d_in[11];
  const float* be2b = (const float*)d_in[12];
  const float* w3a = (const float*)d_in[13];
  const float* b3a = (const float*)d_in[14];
  const float* g3a = (const float*)d_in[15];
  const float* be3a = (const float*)d_in[16];
  const float* w3b = (const float*)d_in[17];
  const float* b3b = (const float*)d_in[18];
  const float* g3b = (const float*)d_in[19];
  const float* be3b = (const float*)d_in[20];
  const float* w4 = (const float*)d_in[21];
  const float* b4 = (const float*)d_in[22];
  float* out = (float*)d_out;

  const int B = 4096, IN = 10338, INP = 10368, H = 1024;
  const int OUTN = 229, OUTP = 256;
  const int RB = 8;
  const int S_BIG = 2, S_MID = 2, S_HEAD = 8;  // all grids = 512 blocks

  char* p = (char*)d_ws;
  auto alloc = [&](size_t bytes) -> void* {
    void* r = (void*)p;
    p += (bytes + 255) & ~(size_t)255;
    return r;
  };
  float* Cpart = (float*)alloc((size_t)S_HEAD * B * H * 4 / 4 * 4);  // 32 MB max
  float* Y = (float*)alloc((size_t)B * H * 4);
  float* Hf = (float*)alloc((size_t)B * H * 4);
  _Float16* xh = (_Float16*)alloc((size_t)B * INP * 2);
  _Float16* xl = (_Float16*)alloc((size_t)B * INP * 2);
  _Float16* w1h = (_Float16*)alloc((size_t)H * INP * 2);
  _Float16* w1l = (_Float16*)alloc((size_t)H * INP * 2);
  _Float16 *wmh[4], *wml[4];
  for (int i = 0; i < 4; ++i) {
    wmh[i] = (_Float16*)alloc((size_t)H * H * 2);
    wml[i] = (_Float16*)alloc((size_t)H * H * 2);
  }
  _Float16* w4h = (_Float16*)alloc((size_t)OUTP * H * 2);
  _Float16* w4l = (_Float16*)alloc((size_t)OUTP * H * 2);
  _Float16* hh = (_Float16*)alloc((size_t)B * H * 2);
  _Float16* hl = (_Float16*)alloc((size_t)B * H * 2);
  float* psum = (float*)alloc((size_t)RB * H * 4);
  float* psq = (float*)alloc((size_t)RB * H * 4);

  // ---- input conversions ----
  {
    int total = B * INP;
    split_pad<<<dim3((total + 255) / 256), 256, 0, stream>>>(x, xh, xl, IN,
                                                             INP, total);
    transpose_split<<<dim3(INP / 32, H / 32), dim3(32, 8), 0, stream>>>(
        w1, w1h, w1l, IN, H, INP, H);
    const float* wm[4] = {w2a, w2b, w3a, w3b};
    for (int i = 0; i < 4; ++i)
      transpose_split<<<dim3(H / 32, H / 32), dim3(32, 8), 0, stream>>>(
          wm[i], wmh[i], wml[i], H, H, H, H);
    transpose_split<<<dim3(H / 32, OUTP / 32), dim3(32, 8), 0, stream>>>(
        w4, w4h, w4l, H, OUTN, H, OUTP);
  }

  auto gemm = [&](const _Float16* Ah, const _Float16* Al, const _Float16* Bh,
                  const _Float16* Bl, int Kld, int Npad, int S) {
    size_t stride = (size_t)B * Npad;
    gemm_sk<<<dim3(B / 128, Npad / 128, S), 256, 0, stream>>>(
        Ah, Al, Bh, Bl, Cpart, Kld, Npad, Kld / S, stride);
  };
  auto reducestats = [&](const float* bias, int S) {
    reduce_bias_stats<<<dim3(H / 64, RB), 256, 0, stream>>>(
        Cpart, bias, Y, psum, psq, H, S, (size_t)B * H, B / RB);
  };
  auto bnapply = [&](const float* g, const float* be, const float* res,
                     float* outf) {
    bn_apply_split<<<dim3(H / 256, B / 4), 256, 0, stream>>>(
        Y, psum, psq, g, be, res, outf, hh, hl, H, RB, 1.f / B);
  };

  // layer 1
  gemm(xh, xl, w1h, w1l, INP, H, S_BIG);
  reducestats(b1, S_BIG);
  bnapply(g1, be1, nullptr, Hf);
  // resblock 2
  gemm(hh, hl, wmh[0], wml[0], H, H, S_MID);
  reducestats(b2a, S_MID);
  bnapply(g2a, be2a, nullptr, nullptr);
  gemm(hh, hl, wmh[1], wml[1], H, H, S_MID);
  reducestats(b2b, S_MID);
  bnapply(g2b, be2b, Hf, Hf);
  // resblock 3
  gemm(hh, hl, wmh[2], wml[2], H, H, S_MID);
  reducestats(b3a, S_MID);
  bnapply(g3a, be3a, nullptr, nullptr);
  gemm(hh, hl, wmh[3], wml[3], H, H, S_MID);
  reducestats(b3b, S_MID);
  bnapply(g3b, be3b, Hf, Hf);
  // head
  gemm(hh, hl, w4h, w4l, H, OUTP, S_HEAD);
  {
    int total = B * OUTP;
    reduce_bias_head<<<dim3((total + 255) / 256), 256, 0, stream>>>(
        Cpart, b4, Y, total, OUTP, OUTN, S_HEAD, (size_t)B * OUTP);
  }

  int nmat = B * 24;
  int ntot = nmat + B * 13;
  polar_tail<<<dim3((ntot + 255) / 256), 256, 0, stream>>>(Y, out, B, nmat,
                                                           OUTP);
}

// Round 4
// 1001.080 us; speedup vs baseline: 4.4833x; 1.4417x over previous
//
#include <hip/hip_runtime.h>
#include <math.h>

// ---------------------------------------------------------------------------
// B=4096, IN=10338 (pad 10368), H=1024, OUT=229 (pad 256)
// R4: same f16x3 split-MFMA GEMM (at m97-structure plateau, 916 TF issued),
//     but: distinct kernel names per GEMM (profiling!), vectorized
//     conversions (half8/half4 stores), single transpose_all kernel,
//     float4 reduce/bn chains.
// ---------------------------------------------------------------------------

typedef _Float16 half8 __attribute__((ext_vector_type(8)));
typedef _Float16 half4_t __attribute__((ext_vector_type(4)));
typedef float floatx4 __attribute__((ext_vector_type(4)));

#define LO_SCALE 4096.0f
#define LO_INV (1.0f / 4096.0f)
#define IN_C 10338
#define INP_C 10368

__device__ __forceinline__ void gld16(const _Float16* g, _Float16* l) {
  __builtin_amdgcn_global_load_lds(
      (const __attribute__((address_space(1))) void*)g,
      (__attribute__((address_space(3))) void*)l, 16, 0, 0);
}

// C_partial[z] = A[M x Ks] * BT[N x Ks]^T  (f16 hi/lo, lo prescaled by 4096)
// TAG distinguishes big/mid/head in profiles.
template <int TAG>
__global__ __launch_bounds__(256, 2)
void gemm_sk(const _Float16* __restrict__ Ah, const _Float16* __restrict__ Al,
             const _Float16* __restrict__ Bh, const _Float16* __restrict__ Bl,
             float* __restrict__ Cp, int Kld, int Ncols, int Ks,
             size_t partStride) {
  __shared__ _Float16 sAh[2][4096], sAl[2][4096];
  __shared__ _Float16 sBh[2][4096], sBl[2][4096];
  const int tid = threadIdx.x;
  const int wv = tid >> 6, ln = tid & 63;
  const int ln15 = ln & 15, q = ln >> 4;
  const int wr = wv >> 1, wc = wv & 1;
  const int bm0 = blockIdx.x * 128, bn0 = blockIdx.y * 128;
  const int k0 = blockIdx.z * Ks;
  Cp += (size_t)blockIdx.z * partStride;

  // staging: source-permuted so fixed lane->LDS placement yields XOR-swizzle
  const int srow = ln >> 2;
  const int swzw = (ln & 3) ^ (srow & 3) ^ ((srow >> 2) & 3);
  const int ch0 = wv * 2, ch1 = wv * 2 + 1;
  const size_t offA0 = (size_t)(bm0 + ch0 * 16 + srow) * Kld + k0 + swzw * 8;
  const size_t offA1 = (size_t)(bm0 + ch1 * 16 + srow) * Kld + k0 + swzw * 8;
  const size_t offB0 = (size_t)(bn0 + ch0 * 16 + srow) * Kld + k0 + swzw * 8;
  const size_t offB1 = (size_t)(bn0 + ch1 * 16 + srow) * Kld + k0 + swzw * 8;

  // fragment reads: de-swizzle
  const int swzr = (q ^ (ln15 & 3) ^ ((ln15 >> 2) & 3)) * 8;
  const int aoff = (wr * 64 + ln15) * 32 + swzr;
  const int boff = (wc * 64 + ln15) * 32 + swzr;

  floatx4 acc[4][4];
  floatx4 acc2[4][4];
#pragma unroll
  for (int i = 0; i < 4; ++i)
#pragma unroll
    for (int j = 0; j < 4; ++j) {
      acc[i][j] = (floatx4){0.f, 0.f, 0.f, 0.f};
      acc2[i][j] = (floatx4){0.f, 0.f, 0.f, 0.f};
    }

  auto stage = [&](int kt, int buf) {
    gld16(Ah + offA0 + kt, &sAh[buf][ch0 * 512]);
    gld16(Ah + offA1 + kt, &sAh[buf][ch1 * 512]);
    gld16(Al + offA0 + kt, &sAl[buf][ch0 * 512]);
    gld16(Al + offA1 + kt, &sAl[buf][ch1 * 512]);
    gld16(Bh + offB0 + kt, &sBh[buf][ch0 * 512]);
    gld16(Bh + offB1 + kt, &sBh[buf][ch1 * 512]);
    gld16(Bl + offB0 + kt, &sBl[buf][ch0 * 512]);
    gld16(Bl + offB1 + kt, &sBl[buf][ch1 * 512]);
  };

  stage(0, 0);
  int cur = 0;
  for (int kt = 0; kt < Ks; kt += 32) {
    __syncthreads();
    if (kt + 32 < Ks) stage(kt + 32, cur ^ 1);

    const _Float16* pAh = &sAh[cur][aoff];
    const _Float16* pAl = &sAl[cur][aoff];
    const _Float16* pBh = &sBh[cur][boff];
    const _Float16* pBl = &sBl[cur][boff];
    half8 bh[4], bl[4];
#pragma unroll
    for (int ni = 0; ni < 4; ++ni) {
      bh[ni] = *(const half8*)(pBh + ni * 512);
      bl[ni] = *(const half8*)(pBl + ni * 512);
    }
#pragma unroll
    for (int mh = 0; mh < 2; ++mh) {
      half8 ah[2], al[2];
#pragma unroll
      for (int i = 0; i < 2; ++i) {
        ah[i] = *(const half8*)(pAh + (mh * 2 + i) * 512);
        al[i] = *(const half8*)(pAl + (mh * 2 + i) * 512);
      }
#pragma unroll
      for (int i = 0; i < 2; ++i) {
        const int mi = mh * 2 + i;
#pragma unroll
        for (int ni = 0; ni < 4; ++ni) {
          acc[mi][ni] = __builtin_amdgcn_mfma_f32_16x16x32_f16(
              ah[i], bh[ni], acc[mi][ni], 0, 0, 0);
          acc2[mi][ni] = __builtin_amdgcn_mfma_f32_16x16x32_f16(
              ah[i], bl[ni], acc2[mi][ni], 0, 0, 0);
          acc2[mi][ni] = __builtin_amdgcn_mfma_f32_16x16x32_f16(
              al[i], bh[ni], acc2[mi][ni], 0, 0, 0);
        }
      }
    }
    cur ^= 1;
  }

  // C/D layout: col = lane&15, row = (lane>>4)*4 + reg  [m89-verified]
#pragma unroll
  for (int mi = 0; mi < 4; ++mi)
#pragma unroll
    for (int ni = 0; ni < 4; ++ni) {
      const int col = bn0 + wc * 64 + ni * 16 + ln15;
      const int rbase = bm0 + wr * 64 + mi * 16 + q * 4;
#pragma unroll
      for (int r = 0; r < 4; ++r)
        Cp[(size_t)(rbase + r) * Ncols + col] =
            acc[mi][ni][r] + acc2[mi][ni][r] * LO_INV;
    }
}

// ---- x fp32 -> padded f16 hi/lo, 8 dest elems/thread, half8 stores ----
__global__ __launch_bounds__(256)
void split_pad_v(const float* __restrict__ X, _Float16* __restrict__ xh,
                 _Float16* __restrict__ xl, int total8) {
  int di = blockIdx.x * 256 + threadIdx.x;
  if (di >= total8) return;
  int base = di * 8;
  int row = base / INP_C;
  int col0 = base - row * INP_C;
  const float* src = X + (size_t)row * IN_C + col0;
  float v[8];
#pragma unroll
  for (int j = 0; j < 8; ++j) v[j] = (col0 + j < IN_C) ? src[j] : 0.f;
  half8 h, l;
#pragma unroll
  for (int j = 0; j < 8; ++j) {
    _Float16 hh = (_Float16)v[j];
    h[j] = hh;
    l[j] = (_Float16)((v[j] - (float)hh) * LO_SCALE);
  }
  *(half8*)(xh + base) = h;
  *(half8*)(xl + base) = l;
}

// ---- all 6 weight transposes in one kernel: W[K][N] -> WT[Npad][Kpad] ----
struct TJob {
  const float* src;
  _Float16* th;
  _Float16* tl;
  int K, N, Kpad, tK, start;
};
struct TJobs {
  TJob j[6];
};

__global__ __launch_bounds__(256)
void transpose_all(TJobs J) {
  const int b = blockIdx.x;
  int ji = 0;
#pragma unroll
  for (int i = 1; i < 6; ++i)
    if (b >= J.j[i].start) ji = i;
  const TJob job = J.j[ji];
  const int t = b - job.start;
  const int kk0 = (t % job.tK) * 32;
  const int nn0 = (t / job.tK) * 32;

  __shared__ float ts[32][33];
  const int tid = threadIdx.x;
  const int tx = tid & 31, ty = tid >> 5;
#pragma unroll
  for (int r = 0; r < 4; ++r) {
    int kk = kk0 + ty + r * 8;
    int nn = nn0 + tx;
    ts[ty + r * 8][tx] =
        (kk < job.K && nn < job.N) ? job.src[(size_t)kk * job.N + nn] : 0.f;
  }
  __syncthreads();
  const int tw = tid & 7, rw = tid >> 3;
  const int nn = nn0 + rw, kk = kk0 + tw * 4;
  half4_t h, l;
#pragma unroll
  for (int i2 = 0; i2 < 4; ++i2) {
    float v = ts[tw * 4 + i2][rw];
    _Float16 hh = (_Float16)v;
    h[i2] = hh;
    l[i2] = (_Float16)((v - (float)hh) * LO_SCALE);
  }
  size_t o = (size_t)nn * job.Kpad + kk;
  *(half4_t*)(job.th + o) = h;
  *(half4_t*)(job.tl + o) = l;
}

// ---- fused: sum split-K partials + bias -> Y, per-rowband col stats ----
// grid (N/256, RB), block 256 = 64 colgroups(x4) x 4 rowlanes; N=1024
__global__ __launch_bounds__(256)
void reduce_bias_stats_v(const float* __restrict__ Cp,
                         const float* __restrict__ bias, float* __restrict__ Y,
                         float* __restrict__ psum, float* __restrict__ psq,
                         int S, size_t stride, int rowsPer) {
  const int N = 1024;
  const int t = threadIdx.x;
  const int cg = t & 63, rl = t >> 6;
  const int col4 = blockIdx.x * 256 + cg * 4;
  const int r0 = blockIdx.y * rowsPer;
  const floatx4 bs = *(const floatx4*)(bias + col4);
  floatx4 s = {0.f, 0.f, 0.f, 0.f}, qq = {0.f, 0.f, 0.f, 0.f};
  for (int r = r0 + rl; r < r0 + rowsPer; r += 4) {
    size_t i = (size_t)r * N + col4;
    floatx4 v = bs;
    for (int k = 0; k < S; ++k) v += *(const floatx4*)(Cp + k * stride + i);
    *(floatx4*)(Y + i) = v;
    s += v;
    qq += v * v;
  }
  __shared__ floatx4 ls[4][64], lq[4][64];
  ls[rl][cg] = s;
  lq[rl][cg] = qq;
  __syncthreads();
  if (t < 64) {
    floatx4 S4 = ls[0][t] + ls[1][t] + ls[2][t] + ls[3][t];
    floatx4 Q4 = lq[0][t] + lq[1][t] + lq[2][t] + lq[3][t];
    size_t o = (size_t)blockIdx.y * N + blockIdx.x * 256 + t * 4;
    *(floatx4*)(psum + o) = S4;
    *(floatx4*)(psq + o) = Q4;
  }
}

// ---- BN finalize+apply (+res, relu) + f16 hi/lo split; float4/half4 ----
// grid (N/256, B/8); block 256 = 64 colgroups(x4) x 4 rowlanes x 2 rows
__global__ __launch_bounds__(256)
void bn_apply_v(const float* __restrict__ Y, const float* __restrict__ psum,
                const float* __restrict__ psq, const float* __restrict__ g,
                const float* __restrict__ be, const float* __restrict__ res,
                float* __restrict__ outf, _Float16* __restrict__ oh,
                _Float16* __restrict__ ol, int RB, float invM) {
  const int N = 1024;
  const int t = threadIdx.x;
  const int cg = t & 63, rl = t >> 6;
  const int col4 = blockIdx.x * 256 + cg * 4;
  __shared__ floatx4 lA[64], lB[64];
  if (t < 64) {
    int c4 = blockIdx.x * 256 + t * 4;
    floatx4 s = {0.f, 0.f, 0.f, 0.f}, qq = {0.f, 0.f, 0.f, 0.f};
    for (int rb = 0; rb < RB; ++rb) {
      s += *(const floatx4*)(psum + (size_t)rb * N + c4);
      qq += *(const floatx4*)(psq + (size_t)rb * N + c4);
    }
    floatx4 m = s * invM;
    floatx4 var = qq * invM - m * m;
    floatx4 rstd;
#pragma unroll
    for (int i = 0; i < 4; ++i) rstd[i] = rsqrtf(var[i] + 1e-5f);
    floatx4 a = (*(const floatx4*)(g + c4)) * rstd;
    lA[t] = a;
    lB[t] = (*(const floatx4*)(be + c4)) - m * a;
  }
  __syncthreads();
  const floatx4 a = lA[cg], b2 = lB[cg];
#pragma unroll
  for (int rr = 0; rr < 2; ++rr) {
    const int r = blockIdx.y * 8 + rl + rr * 4;
    const size_t i = (size_t)r * N + col4;
    floatx4 v = (*(const floatx4*)(Y + i)) * a + b2;
    if (res) v += *(const floatx4*)(res + i);
#pragma unroll
    for (int ii = 0; ii < 4; ++ii) v[ii] = fmaxf(v[ii], 0.f);
    if (outf) *(floatx4*)(outf + i) = v;
    half4_t h, l;
#pragma unroll
    for (int ii = 0; ii < 4; ++ii) {
      _Float16 hh = (_Float16)v[ii];
      h[ii] = hh;
      l[ii] = (_Float16)((v[ii] - (float)hh) * LO_SCALE);
    }
    *(half4_t*)(oh + i) = h;
    *(half4_t*)(ol + i) = l;
  }
}

// ---- head reduce (no BN): partials + guarded bias -> Y; float4 ----
__global__ void reduce_bias_head_v(const float* __restrict__ Cp,
                                   const float* __restrict__ bias,
                                   float* __restrict__ Y, int total4, int S,
                                   size_t stride) {
  int i4 = blockIdx.x * 256 + threadIdx.x;
  if (i4 >= total4) return;
  size_t i = (size_t)i4 * 4;
  int c = (int)(i & 255);  // OUTP=256
  floatx4 v = {0.f, 0.f, 0.f, 0.f};
  for (int k = 0; k < S; ++k) v += *(const floatx4*)(Cp + k * stride + i);
#pragma unroll
  for (int j = 0; j < 4; ++j) {
    int cc = c + j;
    v[j] += (cc < 229) ? bias[cc] : 0.f;
  }
  *(floatx4*)(Y + i) = v;
}

// ---- polar projection (== U@Vh from SVD) * sign(det), fused with tail ----
__device__ __forceinline__ void cofactor3(const float X[9], float C[9]) {
  C[0] = X[4] * X[8] - X[5] * X[7];
  C[1] = X[5] * X[6] - X[3] * X[8];
  C[2] = X[3] * X[7] - X[4] * X[6];
  C[3] = X[2] * X[7] - X[1] * X[8];
  C[4] = X[0] * X[8] - X[2] * X[6];
  C[5] = X[1] * X[6] - X[0] * X[7];
  C[6] = X[1] * X[5] - X[2] * X[4];
  C[7] = X[2] * X[3] - X[0] * X[5];
  C[8] = X[0] * X[4] - X[1] * X[3];
}

__global__ __launch_bounds__(256)
void polar_tail(const float* __restrict__ Y, float* __restrict__ out, int Bt,
                int nmat, int ldy) {
  int idx = blockIdx.x * blockDim.x + threadIdx.x;
  if (idx < nmat) {
    int s = idx / 24, j = idx % 24;
    const float* a = Y + (size_t)s * ldy + j * 9;
    float A[9], X[9];
#pragma unroll
    for (int k = 0; k < 9; ++k) {
      A[k] = a[k];
      X[k] = A[k];
    }
    double detA = (double)A[0] * ((double)A[4] * A[8] - (double)A[5] * A[7]) -
                  (double)A[1] * ((double)A[3] * A[8] - (double)A[5] * A[6]) +
                  (double)A[2] * ((double)A[3] * A[7] - (double)A[4] * A[6]);
    float sgn = (detA < 0.0) ? -1.f : 1.f;
#pragma unroll 1
    for (int it = 0; it < 12; ++it) {
      float C[9];
      cofactor3(X, C);
      float det = X[0] * C[0] + X[1] * C[1] + X[2] * C[2];
      float ad = fmaxf(fabsf(det), 1e-30f);
      float idet = (det < 0.f ? -1.f : 1.f) / ad;
      float n1 = 0.f, n2 = 0.f;
#pragma unroll
      for (int k = 0; k < 9; ++k) {
        n1 += X[k] * X[k];
        n2 += C[k] * C[k];
      }
      n1 = fmaxf(n1, 1e-30f);
      float zeta = sqrtf(sqrtf(n2 * idet * idet / n1));
      zeta = fminf(fmaxf(zeta, 1e-4f), 1e4f);
      float iz = 0.5f / zeta;
      float hz = 0.5f * zeta;
#pragma unroll
      for (int k = 0; k < 9; ++k) X[k] = hz * X[k] + iz * idet * C[k];
    }
    float* o = out + (size_t)idx * 9;
#pragma unroll
    for (int k = 0; k < 9; ++k) o[k] = X[k] * sgn;
  } else {
    int i = idx - nmat;
    int nb = Bt * 10;
    int nc = Bt * 3;
    if (i < nb) {
      int s = i / 10, k = i % 10;
      out[(size_t)Bt * 216 + i] = Y[(size_t)s * ldy + 216 + k];
    } else if (i < nb + nc) {
      int t = i - nb;
      int s = t / 3, k = t % 3;
      out[(size_t)Bt * 216 + nb + t] = Y[(size_t)s * ldy + 226 + k];
    }
  }
}

// ---------------------------------------------------------------------------
extern "C" void kernel_launch(void* const* d_in, const int* in_sizes, int n_in,
                              void* d_out, int out_size, void* d_ws,
                              size_t ws_size, hipStream_t stream) {
  const float* x = (const float*)d_in[0];
  const float* w1 = (const float*)d_in[1];
  const float* b1 = (const float*)d_in[2];
  const float* g1 = (const float*)d_in[3];
  const float* be1 = (const float*)d_in[4];
  const float* w2a = (const float*)d_in[5];
  const float* b2a = (const float*)d_in[6];
  const float* g2a = (const float*)d_in[7];
  const float* be2a = (const float*)d_in[8];
  const float* w2b = (const float*)d_in[9];
  const float* b2b = (const float*)d_in[10];
  const float* g2b = (const float*)d_in[11];
  const float* be2b = (const float*)d_in[12];
  const float* w3a = (const float*)d_in[13];
  const float* b3a = (const float*)d_in[14];
  const float* g3a = (const float*)d_in[15];
  const float* be3a = (const float*)d_in[16];
  const float* w3b = (const float*)d_in[17];
  const float* b3b = (const float*)d_in[18];
  const float* g3b = (const float*)d_in[19];
  const float* be3b = (const float*)d_in[20];
  const float* w4 = (const float*)d_in[21];
  const float* b4 = (const float*)d_in[22];
  float* out = (float*)d_out;

  const int B = 4096, IN = 10338, INP = 10368, H = 1024;
  const int OUTN = 229, OUTP = 256;
  const int RB = 32;
  const int S_BIG = 2, S_MID = 2, S_HEAD = 8;

  char* p = (char*)d_ws;
  auto alloc = [&](size_t bytes) -> void* {
    void* r = (void*)p;
    p += (bytes + 255) & ~(size_t)255;
    return r;
  };
  float* Cpart = (float*)alloc((size_t)S_HEAD * B * OUTP * 4);  // 33.5 MB
  float* Y = (float*)alloc((size_t)B * H * 4);
  float* Hf = (float*)alloc((size_t)B * H * 4);
  _Float16* xh = (_Float16*)alloc((size_t)B * INP * 2);
  _Float16* xl = (_Float16*)alloc((size_t)B * INP * 2);
  _Float16* w1h = (_Float16*)alloc((size_t)H * INP * 2);
  _Float16* w1l = (_Float16*)alloc((size_t)H * INP * 2);
  _Float16 *wmh[4], *wml[4];
  for (int i = 0; i < 4; ++i) {
    wmh[i] = (_Float16*)alloc((size_t)H * H * 2);
    wml[i] = (_Float16*)alloc((size_t)H * H * 2);
  }
  _Float16* w4h = (_Float16*)alloc((size_t)OUTP * H * 2);
  _Float16* w4l = (_Float16*)alloc((size_t)OUTP * H * 2);
  _Float16* hh = (_Float16*)alloc((size_t)B * H * 2);
  _Float16* hl = (_Float16*)alloc((size_t)B * H * 2);
  float* psum = (float*)alloc((size_t)RB * H * 4);
  float* psq = (float*)alloc((size_t)RB * H * 4);

  // ---- conversions ----
  {
    int total8 = B * INP / 8;
    split_pad_v<<<dim3((total8 + 255) / 256), 256, 0, stream>>>(x, xh, xl,
                                                                total8);
    TJobs J;
    const float* wsrc[6] = {w1, w2a, w2b, w3a, w3b, w4};
    _Float16* th[6] = {w1h, wmh[0], wmh[1], wmh[2], wmh[3], w4h};
    _Float16* tl[6] = {w1l, wml[0], wml[1], wml[2], wml[3], w4l};
    int Ks[6] = {IN, H, H, H, H, H};
    int Ns[6] = {H, H, H, H, H, OUTN};
    int Kpads[6] = {INP, H, H, H, H, H};
    int Npads[6] = {H, H, H, H, H, OUTP};
    int start = 0;
    for (int i = 0; i < 6; ++i) {
      J.j[i].src = wsrc[i];
      J.j[i].th = th[i];
      J.j[i].tl = tl[i];
      J.j[i].K = Ks[i];
      J.j[i].N = Ns[i];
      J.j[i].Kpad = Kpads[i];
      J.j[i].tK = Kpads[i] / 32;
      J.j[i].start = start;
      start += (Kpads[i] / 32) * (Npads[i] / 32);
    }
    transpose_all<<<dim3(start), 256, 0, stream>>>(J);
  }

  auto reducestats = [&](const float* bias, int S) {
    reduce_bias_stats_v<<<dim3(H / 256, RB), 256, 0, stream>>>(
        Cpart, bias, Y, psum, psq, S, (size_t)B * H, B / RB);
  };
  auto bnapply = [&](const float* g, const float* be, const float* res,
                     float* outf) {
    bn_apply_v<<<dim3(H / 256, B / 8), 256, 0, stream>>>(
        Y, psum, psq, g, be, res, outf, hh, hl, RB, 1.f / B);
  };

  // layer 1 (big)
  gemm_sk<0><<<dim3(B / 128, H / 128, S_BIG), 256, 0, stream>>>(
      xh, xl, w1h, w1l, Cpart, INP, H, INP / S_BIG, (size_t)B * H);
  reducestats(b1, S_BIG);
  bnapply(g1, be1, nullptr, Hf);
  // resblock 2
  gemm_sk<1><<<dim3(B / 128, H / 128, S_MID), 256, 0, stream>>>(
      hh, hl, wmh[0], wml[0], Cpart, H, H, H / S_MID, (size_t)B * H);
  reducestats(b2a, S_MID);
  bnapply(g2a, be2a, nullptr, nullptr);
  gemm_sk<1><<<dim3(B / 128, H / 128, S_MID), 256, 0, stream>>>(
      hh, hl, wmh[1], wml[1], Cpart, H, H, H / S_MID, (size_t)B * H);
  reducestats(b2b, S_MID);
  bnapply(g2b, be2b, Hf, Hf);
  // resblock 3
  gemm_sk<1><<<dim3(B / 128, H / 128, S_MID), 256, 0, stream>>>(
      hh, hl, wmh[2], wml[2], Cpart, H, H, H / S_MID, (size_t)B * H);
  reducestats(b3a, S_MID);
  bnapply(g3a, be3a, nullptr, nullptr);
  gemm_sk<1><<<dim3(B / 128, H / 128, S_MID), 256, 0, stream>>>(
      hh, hl, wmh[3], wml[3], Cpart, H, H, H / S_MID, (size_t)B * H);
  reducestats(b3b, S_MID);
  bnapply(g3b, be3b, Hf, Hf);
  // head
  gemm_sk<2><<<dim3(B / 128, OUTP / 128, S_HEAD), 256, 0, stream>>>(
      hh, hl, w4h, w4l, Cpart, H, OUTP, H / S_HEAD, (size_t)B * OUTP);
  {
    int total4 = B * OUTP / 4;
    reduce_bias_head_v<<<dim3((total4 + 255) / 256), 256, 0, stream>>>(
        Cpart, b4, Y, total4, S_HEAD, (size_t)B * OUTP);
  }

  int nmat = B * 24;
  int ntot = nmat + B * 13;
  polar_tail<<<dim3((ntot + 255) / 256), 256, 0, stream>>>(Y, out, B, nmat,
                                                           OUTP);
}

// Round 5
// 956.468 us; speedup vs baseline: 4.6925x; 1.0466x over previous
//
#include <hip/hip_runtime.h>
#include <math.h>

// ---------------------------------------------------------------------------
// B=4096, IN=10338 (pad 10368), H=1024, OUT=229 (pad 256)
// R5: f16x3 split-MFMA GEMM + XCD-aware 1-D grid swizzle (B-operand L2
//     locality per XCD), full-GPU reduce grid (512 blocks), head-reduce
//     fused into polar_tail.
// ---------------------------------------------------------------------------

typedef _Float16 half8 __attribute__((ext_vector_type(8)));
typedef _Float16 half4_t __attribute__((ext_vector_type(4)));
typedef float floatx4 __attribute__((ext_vector_type(4)));

#define LO_SCALE 4096.0f
#define LO_INV (1.0f / 4096.0f)
#define IN_C 10338
#define INP_C 10368

__device__ __forceinline__ void gld16(const _Float16* g, _Float16* l) {
  __builtin_amdgcn_global_load_lds(
      (const __attribute__((address_space(1))) void*)g,
      (__attribute__((address_space(3))) void*)l, 16, 0, 0);
}

// C_partial[z] = A[M x Ks] * BT[N x Ks]^T  (f16 hi/lo, lo prescaled by 4096)
// 1-D grid of 512 blocks; XCD-aware decode: xcd = gid&7 owns yz in
// {xcd, xcd+8} only -> per-XCD B working set is 2 N/z slices (L2-resident).
// TAG: 0=big, 1=mid, 2=head (distinct names for profiling).
template <int TAG, int NY>
__global__ __launch_bounds__(256, 2)
void gemm_sk(const _Float16* __restrict__ Ah, const _Float16* __restrict__ Al,
             const _Float16* __restrict__ Bh, const _Float16* __restrict__ Bl,
             float* __restrict__ Cp, int Kld, int Ncols, int Ks,
             size_t partStride) {
  __shared__ _Float16 sAh[2][4096], sAl[2][4096];
  __shared__ _Float16 sBh[2][4096], sBl[2][4096];
  const int tid = threadIdx.x;
  const int wv = tid >> 6, ln = tid & 63;
  const int ln15 = ln & 15, q = ln >> 4;
  const int wr = wv >> 1, wc = wv & 1;

  const int gid = blockIdx.x;
  const int slot = gid >> 3;
  const int yz = (gid & 7) + 8 * (slot & 1);
  const int bm0 = (slot >> 1) * 128;
  const int bn0 = (yz % NY) * 128;
  const int bz = yz / NY;
  const int k0 = bz * Ks;
  Cp += (size_t)bz * partStride;

  // staging: source-permuted so fixed lane->LDS placement yields XOR-swizzle
  const int srow = ln >> 2;
  const int swzw = (ln & 3) ^ (srow & 3) ^ ((srow >> 2) & 3);
  const int ch0 = wv * 2, ch1 = wv * 2 + 1;
  const size_t offA0 = (size_t)(bm0 + ch0 * 16 + srow) * Kld + k0 + swzw * 8;
  const size_t offA1 = (size_t)(bm0 + ch1 * 16 + srow) * Kld + k0 + swzw * 8;
  const size_t offB0 = (size_t)(bn0 + ch0 * 16 + srow) * Kld + k0 + swzw * 8;
  const size_t offB1 = (size_t)(bn0 + ch1 * 16 + srow) * Kld + k0 + swzw * 8;

  // fragment reads: de-swizzle
  const int swzr = (q ^ (ln15 & 3) ^ ((ln15 >> 2) & 3)) * 8;
  const int aoff = (wr * 64 + ln15) * 32 + swzr;
  const int boff = (wc * 64 + ln15) * 32 + swzr;

  floatx4 acc[4][4];
  floatx4 acc2[4][4];
#pragma unroll
  for (int i = 0; i < 4; ++i)
#pragma unroll
    for (int j = 0; j < 4; ++j) {
      acc[i][j] = (floatx4){0.f, 0.f, 0.f, 0.f};
      acc2[i][j] = (floatx4){0.f, 0.f, 0.f, 0.f};
    }

  auto stage = [&](int kt, int buf) {
    gld16(Ah + offA0 + kt, &sAh[buf][ch0 * 512]);
    gld16(Ah + offA1 + kt, &sAh[buf][ch1 * 512]);
    gld16(Al + offA0 + kt, &sAl[buf][ch0 * 512]);
    gld16(Al + offA1 + kt, &sAl[buf][ch1 * 512]);
    gld16(Bh + offB0 + kt, &sBh[buf][ch0 * 512]);
    gld16(Bh + offB1 + kt, &sBh[buf][ch1 * 512]);
    gld16(Bl + offB0 + kt, &sBl[buf][ch0 * 512]);
    gld16(Bl + offB1 + kt, &sBl[buf][ch1 * 512]);
  };

  stage(0, 0);
  int cur = 0;
  for (int kt = 0; kt < Ks; kt += 32) {
    __syncthreads();
    if (kt + 32 < Ks) stage(kt + 32, cur ^ 1);

    const _Float16* pAh = &sAh[cur][aoff];
    const _Float16* pAl = &sAl[cur][aoff];
    const _Float16* pBh = &sBh[cur][boff];
    const _Float16* pBl = &sBl[cur][boff];
    half8 bh[4], bl[4];
#pragma unroll
    for (int ni = 0; ni < 4; ++ni) {
      bh[ni] = *(const half8*)(pBh + ni * 512);
      bl[ni] = *(const half8*)(pBl + ni * 512);
    }
#pragma unroll
    for (int mh = 0; mh < 2; ++mh) {
      half8 ah[2], al[2];
#pragma unroll
      for (int i = 0; i < 2; ++i) {
        ah[i] = *(const half8*)(pAh + (mh * 2 + i) * 512);
        al[i] = *(const half8*)(pAl + (mh * 2 + i) * 512);
      }
#pragma unroll
      for (int i = 0; i < 2; ++i) {
        const int mi = mh * 2 + i;
#pragma unroll
        for (int ni = 0; ni < 4; ++ni) {
          acc[mi][ni] = __builtin_amdgcn_mfma_f32_16x16x32_f16(
              ah[i], bh[ni], acc[mi][ni], 0, 0, 0);
          acc2[mi][ni] = __builtin_amdgcn_mfma_f32_16x16x32_f16(
              ah[i], bl[ni], acc2[mi][ni], 0, 0, 0);
          acc2[mi][ni] = __builtin_amdgcn_mfma_f32_16x16x32_f16(
              al[i], bh[ni], acc2[mi][ni], 0, 0, 0);
        }
      }
    }
    cur ^= 1;
  }

  // C/D layout: col = lane&15, row = (lane>>4)*4 + reg  [m89-verified]
#pragma unroll
  for (int mi = 0; mi < 4; ++mi)
#pragma unroll
    for (int ni = 0; ni < 4; ++ni) {
      const int col = bn0 + wc * 64 + ni * 16 + ln15;
      const int rbase = bm0 + wr * 64 + mi * 16 + q * 4;
#pragma unroll
      for (int r = 0; r < 4; ++r)
        Cp[(size_t)(rbase + r) * Ncols + col] =
            acc[mi][ni][r] + acc2[mi][ni][r] * LO_INV;
    }
}

// ---- x fp32 -> padded f16 hi/lo, 8 dest elems/thread, half8 stores ----
__global__ __launch_bounds__(256)
void split_pad_v(const float* __restrict__ X, _Float16* __restrict__ xh,
                 _Float16* __restrict__ xl, int total8) {
  int di = blockIdx.x * 256 + threadIdx.x;
  if (di >= total8) return;
  int base = di * 8;
  int row = base / INP_C;
  int col0 = base - row * INP_C;
  const float* src = X + (size_t)row * IN_C + col0;
  float v[8];
#pragma unroll
  for (int j = 0; j < 8; ++j) v[j] = (col0 + j < IN_C) ? src[j] : 0.f;
  half8 h, l;
#pragma unroll
  for (int j = 0; j < 8; ++j) {
    _Float16 hh = (_Float16)v[j];
    h[j] = hh;
    l[j] = (_Float16)((v[j] - (float)hh) * LO_SCALE);
  }
  *(half8*)(xh + base) = h;
  *(half8*)(xl + base) = l;
}

// ---- all 6 weight transposes in one kernel: W[K][N] -> WT[Npad][Kpad] ----
struct TJob {
  const float* src;
  _Float16* th;
  _Float16* tl;
  int K, N, Kpad, tK, start;
};
struct TJobs {
  TJob j[6];
};

__global__ __launch_bounds__(256)
void transpose_all(TJobs J) {
  const int b = blockIdx.x;
  int ji = 0;
#pragma unroll
  for (int i = 1; i < 6; ++i)
    if (b >= J.j[i].start) ji = i;
  const TJob job = J.j[ji];
  const int t = b - job.start;
  const int kk0 = (t % job.tK) * 32;
  const int nn0 = (t / job.tK) * 32;

  __shared__ float ts[32][33];
  const int tid = threadIdx.x;
  const int tx = tid & 31, ty = tid >> 5;
#pragma unroll
  for (int r = 0; r < 4; ++r) {
    int kk = kk0 + ty + r * 8;
    int nn = nn0 + tx;
    ts[ty + r * 8][tx] =
        (kk < job.K && nn < job.N) ? job.src[(size_t)kk * job.N + nn] : 0.f;
  }
  __syncthreads();
  const int tw = tid & 7, rw = tid >> 3;
  const int nn = nn0 + rw, kk = kk0 + tw * 4;
  half4_t h, l;
#pragma unroll
  for (int i2 = 0; i2 < 4; ++i2) {
    float v = ts[tw * 4 + i2][rw];
    _Float16 hh = (_Float16)v;
    h[i2] = hh;
    l[i2] = (_Float16)((v - (float)hh) * LO_SCALE);
  }
  size_t o = (size_t)nn * job.Kpad + kk;
  *(half4_t*)(job.th + o) = h;
  *(half4_t*)(job.tl + o) = l;
}

// ---- fused: sum split-K partials + bias -> Y, per-rowband col stats ----
// grid (16, 32) = 512 blocks; block = 16 colgroups(x4 cols) x 16 rowlanes
__global__ __launch_bounds__(256)
void reduce_bias_stats_v(const float* __restrict__ Cp,
                         const float* __restrict__ bias, float* __restrict__ Y,
                         float* __restrict__ psum, float* __restrict__ psq,
                         int S, size_t stride, int rowsPer) {
  const int N = 1024;
  const int t = threadIdx.x;
  const int cg = t & 15, rl = t >> 4;
  const int col4 = blockIdx.x * 64 + cg * 4;
  const int r0 = blockIdx.y * rowsPer;
  const floatx4 bs = *(const floatx4*)(bias + col4);
  floatx4 s = {0.f, 0.f, 0.f, 0.f}, qq = {0.f, 0.f, 0.f, 0.f};
  for (int r = r0 + rl; r < r0 + rowsPer; r += 16) {
    size_t i = (size_t)r * N + col4;
    floatx4 v = bs;
    for (int k = 0; k < S; ++k) v += *(const floatx4*)(Cp + k * stride + i);
    *(floatx4*)(Y + i) = v;
    s += v;
    qq += v * v;
  }
  __shared__ floatx4 ls[16][16], lq[16][16];
  ls[rl][cg] = s;
  lq[rl][cg] = qq;
  __syncthreads();
  if (t < 16) {
    floatx4 S4 = {0.f, 0.f, 0.f, 0.f}, Q4 = {0.f, 0.f, 0.f, 0.f};
#pragma unroll
    for (int r = 0; r < 16; ++r) {
      S4 += ls[r][t];
      Q4 += lq[r][t];
    }
    size_t o = (size_t)blockIdx.y * N + blockIdx.x * 64 + t * 4;
    *(floatx4*)(psum + o) = S4;
    *(floatx4*)(psq + o) = Q4;
  }
}

// ---- BN finalize+apply (+res, relu) + f16 hi/lo split; float4/half4 ----
__global__ __launch_bounds__(256)
void bn_apply_v(const float* __restrict__ Y, const float* __restrict__ psum,
                const float* __restrict__ psq, const float* __restrict__ g,
                const float* __restrict__ be, const float* __restrict__ res,
                float* __restrict__ outf, _Float16* __restrict__ oh,
                _Float16* __restrict__ ol, int RB, float invM) {
  const int N = 1024;
  const int t = threadIdx.x;
  const int cg = t & 63, rl = t >> 6;
  const int col4 = blockIdx.x * 256 + cg * 4;
  __shared__ floatx4 lA[64], lB[64];
  if (t < 64) {
    int c4 = blockIdx.x * 256 + t * 4;
    floatx4 s = {0.f, 0.f, 0.f, 0.f}, qq = {0.f, 0.f, 0.f, 0.f};
    for (int rb = 0; rb < RB; ++rb) {
      s += *(const floatx4*)(psum + (size_t)rb * N + c4);
      qq += *(const floatx4*)(psq + (size_t)rb * N + c4);
    }
    floatx4 m = s * invM;
    floatx4 var = qq * invM - m * m;
    floatx4 rstd;
#pragma unroll
    for (int i = 0; i < 4; ++i) rstd[i] = rsqrtf(var[i] + 1e-5f);
    floatx4 a = (*(const floatx4*)(g + c4)) * rstd;
    lA[t] = a;
    lB[t] = (*(const floatx4*)(be + c4)) - m * a;
  }
  __syncthreads();
  const floatx4 a = lA[cg], b2 = lB[cg];
#pragma unroll
  for (int rr = 0; rr < 2; ++rr) {
    const int r = blockIdx.y * 8 + rl + rr * 4;
    const size_t i = (size_t)r * N + col4;
    floatx4 v = (*(const floatx4*)(Y + i)) * a + b2;
    if (res) v += *(const floatx4*)(res + i);
#pragma unroll
    for (int ii = 0; ii < 4; ++ii) v[ii] = fmaxf(v[ii], 0.f);
    if (outf) *(floatx4*)(outf + i) = v;
    half4_t h, l;
#pragma unroll
    for (int ii = 0; ii < 4; ++ii) {
      _Float16 hh = (_Float16)v[ii];
      h[ii] = hh;
      l[ii] = (_Float16)((v[ii] - (float)hh) * LO_SCALE);
    }
    *(half4_t*)(oh + i) = h;
    *(half4_t*)(ol + i) = l;
  }
}

// ---- polar projection (== U@Vh from SVD) * sign(det), fused with head
//      split-K reduce + bias and the betas/camera tail copy ----
__device__ __forceinline__ void cofactor3(const float X[9], float C[9]) {
  C[0] = X[4] * X[8] - X[5] * X[7];
  C[1] = X[5] * X[6] - X[3] * X[8];
  C[2] = X[3] * X[7] - X[4] * X[6];
  C[3] = X[2] * X[7] - X[1] * X[8];
  C[4] = X[0] * X[8] - X[2] * X[6];
  C[5] = X[1] * X[6] - X[0] * X[7];
  C[6] = X[1] * X[5] - X[2] * X[4];
  C[7] = X[2] * X[3] - X[0] * X[5];
  C[8] = X[0] * X[4] - X[1] * X[3];
}

__global__ __launch_bounds__(256)
void polar_tail(const float* __restrict__ Cp, const float* __restrict__ bias,
                float* __restrict__ out, int Bt, int nmat, int S,
                size_t stride) {
  const int ldy = 256;
  int idx = blockIdx.x * blockDim.x + threadIdx.x;
  if (idx < nmat) {
    int s = idx / 24, j = idx % 24;
    const size_t base = (size_t)s * ldy + j * 9;
    float A[9], X[9];
#pragma unroll
    for (int k = 0; k < 9; ++k) {
      float v = bias[j * 9 + k];
      for (int z = 0; z < S; ++z) v += Cp[z * stride + base + k];
      A[k] = v;
      X[k] = v;
    }
    double detA = (double)A[0] * ((double)A[4] * A[8] - (double)A[5] * A[7]) -
                  (double)A[1] * ((double)A[3] * A[8] - (double)A[5] * A[6]) +
                  (double)A[2] * ((double)A[3] * A[7] - (double)A[4] * A[6]);
    float sgn = (detA < 0.0) ? -1.f : 1.f;
#pragma unroll 1
    for (int it = 0; it < 12; ++it) {
      float C[9];
      cofactor3(X, C);
      float det = X[0] * C[0] + X[1] * C[1] + X[2] * C[2];
      float ad = fmaxf(fabsf(det), 1e-30f);
      float idet = (det < 0.f ? -1.f : 1.f) / ad;
      float n1 = 0.f, n2 = 0.f;
#pragma unroll
      for (int k = 0; k < 9; ++k) {
        n1 += X[k] * X[k];
        n2 += C[k] * C[k];
      }
      n1 = fmaxf(n1, 1e-30f);
      float zeta = sqrtf(sqrtf(n2 * idet * idet / n1));
      zeta = fminf(fmaxf(zeta, 1e-4f), 1e4f);
      float iz = 0.5f / zeta;
      float hz = 0.5f * zeta;
#pragma unroll
      for (int k = 0; k < 9; ++k) X[k] = hz * X[k] + iz * idet * C[k];
    }
    float* o = out + (size_t)idx * 9;
#pragma unroll
    for (int k = 0; k < 9; ++k) o[k] = X[k] * sgn;
  } else {
    int i = idx - nmat;
    int nb = Bt * 10;
    int nc = Bt * 3;
    int s, k, c;
    if (i < nb) {
      s = i / 10;
      k = i;
      c = 216 + (i % 10);
    } else if (i < nb + nc) {
      int t2 = i - nb;
      s = t2 / 3;
      k = i;
      c = 226 + (t2 % 3);
    } else {
      return;
    }
    float v = bias[c];
    size_t base = (size_t)s * ldy + c;
    for (int z = 0; z < S; ++z) v += Cp[z * stride + base];
    out[(size_t)Bt * 216 + k] = v;
  }
}

// ---------------------------------------------------------------------------
extern "C" void kernel_launch(void* const* d_in, const int* in_sizes, int n_in,
                              void* d_out, int out_size, void* d_ws,
                              size_t ws_size, hipStream_t stream) {
  const float* x = (const float*)d_in[0];
  const float* w1 = (const float*)d_in[1];
  const float* b1 = (const float*)d_in[2];
  const float* g1 = (const float*)d_in[3];
  const float* be1 = (const float*)d_in[4];
  const float* w2a = (const float*)d_in[5];
  const float* b2a = (const float*)d_in[6];
  const float* g2a = (const float*)d_in[7];
  const float* be2a = (const float*)d_in[8];
  const float* w2b = (const float*)d_in[9];
  const float* b2b = (const float*)d_in[10];
  const float* g2b = (const float*)d_in[11];
  const float* be2b = (const float*)d_in[12];
  const float* w3a = (const float*)d_in[13];
  const float* b3a = (const float*)d_in[14];
  const float* g3a = (const float*)d_in[15];
  const float* be3a = (const float*)d_in[16];
  const float* w3b = (const float*)d_in[17];
  const float* b3b = (const float*)d_in[18];
  const float* g3b = (const float*)d_in[19];
  const float* be3b = (const float*)d_in[20];
  const float* w4 = (const float*)d_in[21];
  const float* b4 = (const float*)d_in[22];
  float* out = (float*)d_out;

  const int B = 4096, IN = 10338, INP = 10368, H = 1024;
  const int OUTN = 229, OUTP = 256;
  const int RB = 32;
  const int S_BIG = 2, S_MID = 2, S_HEAD = 8;

  char* p = (char*)d_ws;
  auto alloc = [&](size_t bytes) -> void* {
    void* r = (void*)p;
    p += (bytes + 255) & ~(size_t)255;
    return r;
  };
  float* Cpart = (float*)alloc((size_t)S_HEAD * B * OUTP * 4);  // 33.5 MB
  float* Y = (float*)alloc((size_t)B * H * 4);
  float* Hf = (float*)alloc((size_t)B * H * 4);
  _Float16* xh = (_Float16*)alloc((size_t)B * INP * 2);
  _Float16* xl = (_Float16*)alloc((size_t)B * INP * 2);
  _Float16* w1h = (_Float16*)alloc((size_t)H * INP * 2);
  _Float16* w1l = (_Float16*)alloc((size_t)H * INP * 2);
  _Float16 *wmh[4], *wml[4];
  for (int i = 0; i < 4; ++i) {
    wmh[i] = (_Float16*)alloc((size_t)H * H * 2);
    wml[i] = (_Float16*)alloc((size_t)H * H * 2);
  }
  _Float16* w4h = (_Float16*)alloc((size_t)OUTP * H * 2);
  _Float16* w4l = (_Float16*)alloc((size_t)OUTP * H * 2);
  _Float16* hh = (_Float16*)alloc((size_t)B * H * 2);
  _Float16* hl = (_Float16*)alloc((size_t)B * H * 2);
  float* psum = (float*)alloc((size_t)RB * H * 4);
  float* psq = (float*)alloc((size_t)RB * H * 4);

  // ---- conversions ----
  {
    int total8 = B * INP / 8;
    split_pad_v<<<dim3((total8 + 255) / 256), 256, 0, stream>>>(x, xh, xl,
                                                                total8);
    TJobs J;
    const float* wsrc[6] = {w1, w2a, w2b, w3a, w3b, w4};
    _Float16* th[6] = {w1h, wmh[0], wmh[1], wmh[2], wmh[3], w4h};
    _Float16* tl[6] = {w1l, wml[0], wml[1], wml[2], wml[3], w4l};
    int Ks[6] = {IN, H, H, H, H, H};
    int Ns[6] = {H, H, H, H, H, OUTN};
    int Kpads[6] = {INP, H, H, H, H, H};
    int Npads[6] = {H, H, H, H, H, OUTP};
    int start = 0;
    for (int i = 0; i < 6; ++i) {
      J.j[i].src = wsrc[i];
      J.j[i].th = th[i];
      J.j[i].tl = tl[i];
      J.j[i].K = Ks[i];
      J.j[i].N = Ns[i];
      J.j[i].Kpad = Kpads[i];
      J.j[i].tK = Kpads[i] / 32;
      J.j[i].start = start;
      start += (Kpads[i] / 32) * (Npads[i] / 32);
    }
    transpose_all<<<dim3(start), 256, 0, stream>>>(J);
  }

  auto reducestats = [&](const float* bias, int S) {
    reduce_bias_stats_v<<<dim3(16, RB), 256, 0, stream>>>(
        Cpart, bias, Y, psum, psq, S, (size_t)B * H, B / RB);
  };
  auto bnapply = [&](const float* g, const float* be, const float* res,
                     float* outf) {
    bn_apply_v<<<dim3(H / 256, B / 8), 256, 0, stream>>>(
        Y, psum, psq, g, be, res, outf, hh, hl, RB, 1.f / B);
  };

  // layer 1 (big): grid 512 = 32 M x 8 N x 2 S
  gemm_sk<0, 8><<<dim3(512), 256, 0, stream>>>(xh, xl, w1h, w1l, Cpart, INP, H,
                                               INP / S_BIG, (size_t)B * H);
  reducestats(b1, S_BIG);
  bnapply(g1, be1, nullptr, Hf);
  // resblock 2
  gemm_sk<1, 8><<<dim3(512), 256, 0, stream>>>(hh, hl, wmh[0], wml[0], Cpart,
                                               H, H, H / S_MID, (size_t)B * H);
  reducestats(b2a, S_MID);
  bnapply(g2a, be2a, nullptr, nullptr);
  gemm_sk<1, 8><<<dim3(512), 256, 0, stream>>>(hh, hl, wmh[1], wml[1], Cpart,
                                               H, H, H / S_MID, (size_t)B * H);
  reducestats(b2b, S_MID);
  bnapply(g2b, be2b, Hf, Hf);
  // resblock 3
  gemm_sk<1, 8><<<dim3(512), 256, 0, stream>>>(hh, hl, wmh[2], wml[2], Cpart,
                                               H, H, H / S_MID, (size_t)B * H);
  reducestats(b3a, S_MID);
  bnapply(g3a, be3a, nullptr, nullptr);
  gemm_sk<1, 8><<<dim3(512), 256, 0, stream>>>(hh, hl, wmh[3], wml[3], Cpart,
                                               H, H, H / S_MID, (size_t)B * H);
  reducestats(b3b, S_MID);
  bnapply(g3b, be3b, Hf, Hf);
  // head: grid 512 = 32 M x 2 N x 8 S
  gemm_sk<2, 2><<<dim3(512), 256, 0, stream>>>(hh, hl, w4h, w4l, Cpart, H,
                                               OUTP, H / S_HEAD,
                                               (size_t)B * OUTP);

  int nmat = B * 24;
  int ntot = nmat + B * 13;
  polar_tail<<<dim3((ntot + 255) / 256), 256, 0, stream>>>(
      Cpart, b4, out, B, nmat, S_HEAD, (size_t)B * OUTP);
}